// Round 8
// baseline (4192.622 us; speedup 1.0000x reference)
//
#include <hip/hip_runtime.h>
#include <hip/hip_bf16.h>
#include <stdint.h>

// ---------------- problem constants ----------------
static constexpr int Hd   = 1024;     // H_DIM
static constexpr int BZn  = 256;      // batch
static constexpr int MTOT = 131072;   // 32 * 4096 keys
static constexpr int NU   = 7;        // units

typedef float  f32x4  __attribute__((ext_vector_type(4)));
typedef short  bf16x8 __attribute__((ext_vector_type(8)));
typedef short  bf16x4 __attribute__((ext_vector_type(4)));
typedef unsigned short u16;

__device__ __forceinline__ u16 f2bf(float f) {
    __hip_bfloat16 h = __float2bfloat16(f);   // RNE
    return *reinterpret_cast<u16*>(&h);
}
__device__ __forceinline__ float bf2f(u16 h) {
    return __uint_as_float(((unsigned int)h) << 16);
}

// ---------------- prep kernels ----------------

// Qrot[256][1024] = query @ R  (f32). 64 blocks x 256.
__global__ void k_qrot(const float* __restrict__ query, const float* __restrict__ R,
                       float* __restrict__ Qrot) {
    __shared__ float qt[4][Hd];
    const int t = threadIdx.x;
    const int r0 = blockIdx.x * 4;
    for (int r = 0; r < 4; ++r)
        *(float4*)(&qt[r][t * 4]) = *(const float4*)(query + (long long)(r0 + r) * Hd + t * 4);
    __syncthreads();
    float acc[4][4] = {};
    for (int k = 0; k < Hd; ++k) {
        float4 rv = *(const float4*)(R + (long long)k * Hd + t * 4);
#pragma unroll
        for (int r = 0; r < 4; ++r) {
            float qv = qt[r][k];
            acc[r][0] += qv * rv.x; acc[r][1] += qv * rv.y;
            acc[r][2] += qv * rv.z; acc[r][3] += qv * rv.w;
        }
    }
    for (int r = 0; r < 4; ++r) {
        float4 o; o.x = acc[r][0]; o.y = acc[r][1]; o.z = acc[r][2]; o.w = acc[r][3];
        *(float4*)(Qrot + (long long)(r0 + r) * Hd + t * 4) = o;
    }
}

// Rpack: B-fragment layout for mfma_f32_16x16x32_bf16.
// frag id = (c0/16)*32 + (k0/32); lane l holds B[k0+(l>>4)*8+j][c0+(l&15)], j=0..7.
__global__ void k_rpack(const float* __restrict__ R, u16* __restrict__ Rpack) {
    const int gt = blockIdx.x * 256 + threadIdx.x;
    const int frag = gt >> 6, lam = gt & 63;
    const int cblk = frag >> 5, kblk = frag & 31;
    const int c  = cblk * 16 + (lam & 15);
    const int k0 = kblk * 32 + (lam >> 4) * 8;
    union { bf16x8 v; u16 u[8]; } p;
#pragma unroll
    for (int j = 0; j < 8; ++j) p.u[j] = f2bf(R[(long long)(k0 + j) * Hd + c]);
    *(bf16x8*)(Rpack + (long long)frag * 512 + lam * 8) = p.v;
}

// Qpack: A-fragment layout. frag id = (c0/32)*16 + (q0/16);
// lane l holds A[q0+(l&15)][c0+(l>>4)*8+j].
__global__ void k_qpack(const float* __restrict__ Qrot, u16* __restrict__ Qpack) {
    const int gt = blockIdx.x * 256 + threadIdx.x;
    const int frag = gt >> 6, lam = gt & 63;
    const int cblk = frag >> 4, qblk = frag & 15;
    const int q  = qblk * 16 + (lam & 15);
    const int c0 = cblk * 32 + (lam >> 4) * 8;
    union { bf16x8 v; u16 u[8]; } p;
#pragma unroll
    for (int j = 0; j < 8; ++j) p.u[j] = f2bf(Qrot[(long long)q * Hd + c0 + j]);
    *(bf16x8*)(Qpack + (long long)frag * 512 + lam * 8) = p.v;
}

// ---------------- GEMM 1: rotK = keys @ R (bf16 out) + unit norms ----------------
// 128x128 tile, 256 thr (4 waves), wave = 64keys x 64cols (4x4 frags), BK=32 dbuf.
// grid: bx = cb*1024 + tkey -> all 8 col-blocks of one key-tile on one XCD.
__global__ __launch_bounds__(256, 2)
void k_rot(const float* __restrict__ keys, const u16* __restrict__ Rp,
           u16* __restrict__ rotK, float* __restrict__ norms) {
    __shared__ char abuf[2][10240];     // [128 rows][80 B] per buf

    const int t   = threadIdx.x;
    const int lam = t & 63;
    const int w   = t >> 6;             // 4 waves
    const int l15 = lam & 15;
    const int lg  = lam >> 4;
    const int wq  = w >> 1;             // key half (64)
    const int wc  = w & 1;              // col half (64)

    const int bx   = blockIdx.x;
    const int cb   = bx >> 10;          // col-block 0..7
    const int tkey = bx & 1023;         // key-tile 0..1023
    const int kb   = tkey * 128;

    // A staging: thread t loads 4x float4: row = j*32 + (t>>3), col = (t&7)*4.
    // lane-consecutive float4 -> 8 rows x 128B contiguous per instruction.
    const float* apt = keys + (long long)(kb + (t >> 3)) * Hd + (t & 7) * 4;
    const int sdst = (t >> 3) * 80 + (t & 7) * 8;

    // B-frag stream base: fid = (cb*8 + wc*4 + n)*32 + s
    const char* bB = (const char*)Rp + (long long)((cb * 8 + wc * 4) * 32) * 1024 + lam * 16;

    f32x4 acc[4][4];
#pragma unroll
    for (int m = 0; m < 4; ++m)
#pragma unroll
        for (int n = 0; n < 4; ++n) acc[m][n] = (f32x4){0.f, 0.f, 0.f, 0.f};

    // prologue prefetch (stage 0)
    float4 ar[4];
#pragma unroll
    for (int j = 0; j < 4; ++j) ar[j] = *(const float4*)(apt + (long long)j * 32 * Hd);
    bf16x8 nb[4];
#pragma unroll
    for (int n = 0; n < 4; ++n) nb[n] = *(const bf16x8*)(bB + (long long)(n * 32) * 1024);

#pragma unroll 2
    for (int s = 0; s < 32; ++s) {
        const int buf = s & 1;
        // convert + write staged A (4 x b64)
#pragma unroll
        for (int j = 0; j < 4; ++j) {
            union { bf16x4 v; u16 u[4]; } p;
            p.u[0] = f2bf(ar[j].x); p.u[1] = f2bf(ar[j].y);
            p.u[2] = f2bf(ar[j].z); p.u[3] = f2bf(ar[j].w);
            *(bf16x4*)(&abuf[buf][j * 2560 + sdst]) = p.v;
        }

        // prefetch next stage
        const int sn = (s < 31) ? s + 1 : 31;
#pragma unroll
        for (int j = 0; j < 4; ++j)
            ar[j] = *(const float4*)(apt + (long long)j * 32 * Hd + sn * 32);
        bf16x8 cbv[4];
#pragma unroll
        for (int n = 0; n < 4; ++n) cbv[n] = nb[n];
#pragma unroll
        for (int n = 0; n < 4; ++n)
            nb[n] = *(const bf16x8*)(bB + (long long)(n * 32 + sn) * 1024);

        __syncthreads();   // staged A visible

#pragma unroll
        for (int m = 0; m < 4; ++m) {
            int row = wq * 64 + m * 16 + l15;
            bf16x8 a = *(const bf16x8*)(&abuf[buf][row * 80 + lg * 16]);
#pragma unroll
            for (int n = 0; n < 4; ++n)
                acc[m][n] = __builtin_amdgcn_mfma_f32_16x16x32_bf16(a, cbv[n], acc[m][n], 0, 0, 0);
        }
    }

    // ---- per-(key,unit) sq-norm partials ----
    const int colbase = cb * 128 + wc * 64;
    const int c6 = colbase >> 6;
    const int u = (c6 < 4) ? 0 : (c6 < 8) ? 1 : (c6 < 10) ? 2 : (c6 < 12) ? 3
                : (c6 < 14) ? 4 : (c6 < 15) ? 5 : 6;
#pragma unroll
    for (int m = 0; m < 4; ++m) {
#pragma unroll
        for (int e = 0; e < 4; ++e) {
            const int key = kb + wq * 64 + m * 16 + lg * 4 + e;
            float s = 0.f;
#pragma unroll
            for (int n = 0; n < 4; ++n) { float v = acc[m][n][e]; s = fmaf(v, v, s); }
            s += __shfl_xor(s, 1); s += __shfl_xor(s, 2);
            s += __shfl_xor(s, 4); s += __shfl_xor(s, 8);
            if (l15 == 0) atomicAdd(norms + (long long)key * 8 + u, s);
        }
    }

    // ---- epilogue: LDS bounce -> coalesced rotK stores ----
    // T = 32 rows x 128 cols bf16, stride 272 B (fits in abuf[0][0..8704))
    char* T = &abuf[0][0];
#pragma unroll 1
    for (int m = 0; m < 4; ++m) {
        __syncthreads();   // T free (prev m's reads done; first iter: disjoint from abuf[1])
#pragma unroll
        for (int n = 0; n < 4; ++n) {
            int tcol = wc * 64 + n * 16 + l15;
#pragma unroll
            for (int e = 0; e < 4; ++e) {
                int trow = wq * 16 + lg * 4 + e;
                *(u16*)(T + trow * 272 + tcol * 2) = f2bf(acc[m][n][e]);
            }
        }
        __syncthreads();   // T visible
#pragma unroll
        for (int p = 0; p < 2; ++p) {
            int row = p * 16 + (t >> 4);
            int colc = (t & 15) * 8;
            bf16x8 v = *(const bf16x8*)(T + row * 272 + colc * 2);
            int key = kb + (row >> 4) * 64 + m * 16 + (row & 15);
            *(bf16x8*)(rotK + (long long)key * Hd + cb * 128 + colc) = v;
        }
    }
}

// ---------------- GEMM 2: sims + segmented argmax ----------------
// block = 256 q x 128 keys, 512 thr (8 waves). No LDS, no barriers.
static constexpr unsigned int FMASK = 0xA8888080u;  // flush after ks 7,15,19,23,27,29,31

__global__ __launch_bounds__(512, 2)
void k_sim(const u16* __restrict__ rotK, const u16* __restrict__ Qp,
           const float* __restrict__ norms, unsigned long long* __restrict__ best) {
    const int t   = threadIdx.x;
    const int lam = t & 63;
    const int w   = t >> 6;
    const int l15 = lam & 15;
    const int lg  = lam >> 4;
    const int wq  = w >> 1;             // q quarter (64)
    const int wk  = w & 1;              // key half (64)
    const int key0 = blockIdx.x * 128 + wk * 64;

    const char* QpB = (const char*)Qp;
    const char* KB  = (const char*)rotK;

    f32x4 acc[4][4];
#pragma unroll
    for (int m = 0; m < 4; ++m)
#pragma unroll
        for (int n = 0; n < 4; ++n) acc[m][n] = (f32x4){0.f, 0.f, 0.f, 0.f};

    // depth-1 prefetch
    bf16x8 aqN[4], bkN[4];
#pragma unroll
    for (int m = 0; m < 4; ++m)
        aqN[m] = *(const bf16x8*)(QpB + (long long)(wq * 4 + m) * 1024 + lam * 16);
#pragma unroll
    for (int n = 0; n < 4; ++n)
        bkN[n] = *(const bf16x8*)(KB + (long long)(key0 + n * 16 + l15) * 2048 + lg * 16);

#pragma unroll
    for (int ks = 0; ks < 32; ++ks) {
        bf16x8 aq[4], bk[4];
#pragma unroll
        for (int m = 0; m < 4; ++m) aq[m] = aqN[m];
#pragma unroll
        for (int n = 0; n < 4; ++n) bk[n] = bkN[n];
        if (ks < 31) {
#pragma unroll
            for (int m = 0; m < 4; ++m)
                aqN[m] = *(const bf16x8*)(QpB + (long long)((ks + 1) * 16 + wq * 4 + m) * 1024 + lam * 16);
#pragma unroll
            for (int n = 0; n < 4; ++n)
                bkN[n] = *(const bf16x8*)(KB + (long long)(key0 + n * 16 + l15) * 2048 + (ks + 1) * 64 + lg * 16);
        }
#pragma unroll
        for (int m = 0; m < 4; ++m)
#pragma unroll
            for (int n = 0; n < 4; ++n)
                acc[m][n] = __builtin_amdgcn_mfma_f32_16x16x32_bf16(aq[m], bk[n], acc[m][n], 0, 0, 0);

        if ((FMASK >> ks) & 1) {
            const int u = __popc(FMASK & ((1u << ks) - 1u));
            float rn[4];
#pragma unroll
            for (int n = 0; n < 4; ++n) {
                float nv = norms[(long long)(key0 + n * 16 + l15) * 8 + u];
                rn[n] = 1.0f / fmaxf(sqrtf(nv), 1e-3f);
            }
#pragma unroll
            for (int m = 0; m < 4; ++m) {
#pragma unroll
                for (int e = 0; e < 4; ++e) {
                    float bv = acc[m][0][e] * rn[0];
                    int  bi6 = l15;
#pragma unroll
                    for (int n = 1; n < 4; ++n) {
                        float v = acc[m][n][e] * rn[n];
                        if (v > bv) { bv = v; bi6 = n * 16 + l15; }
                    }
                    unsigned int ui = __float_as_uint(bv);
                    unsigned int mp = ui ^ (((int)ui < 0) ? 0xFFFFFFFFu : 0x80000000u);
                    unsigned int enc = (mp & 0xFFFFFFC0u) | (63u - (unsigned int)bi6);
#pragma unroll
                    for (int mask = 1; mask <= 8; mask <<= 1) {
                        unsigned int o = __shfl_xor(enc, mask);
                        enc = (o > enc) ? o : enc;
                    }
                    if (l15 == 0) {
                        unsigned int gl = (unsigned int)(key0 + (63 - (int)(enc & 63u)));
                        unsigned long long e64 =
                            ((unsigned long long)(enc & 0xFFFFFFC0u) << 32) |
                            (unsigned long long)(0xFFFFFFFFu - gl);
                        int qq = wq * 64 + m * 16 + lg * 4 + e;
                        unsigned long long* addr = best + u * BZn + qq;
                        if (e64 > *addr) atomicMax(addr, e64);
                    }
#pragma unroll
                    for (int n = 0; n < 4; ++n) acc[m][n][e] = 0.f;
                }
            }
        }
    }
}

// ---------------- fallback fused kernel (R6) for small ws ----------------
static constexpr int LDS_TOT_FB = 163840;

__global__ __launch_bounds__(1024, 4)
void k_main_fused(const float* __restrict__ keys, const u16* __restrict__ Rp,
                  const u16* __restrict__ Qp, unsigned long long* __restrict__ best) {
    extern __shared__ char smem[];
    char* keysA = smem;
    char* Krot  = smem + 131072;

    const int t   = threadIdx.x;
    const int lam = t & 63;
    const int w   = t >> 6;
    const int l15 = lam & 15;
    const int lg  = lam >> 4;
    const int cs  = w >> 1;
    const int h   = w & 1;
    const int row0 = blockIdx.x * 64;

    {
        const float* kb = keys + (long long)row0 * Hd;
#pragma unroll
        for (int i = 0; i < 8; ++i) {
            int e0 = i * 8192 + t * 8;
            float4 v0 = *(const float4*)(kb + e0);
            float4 v1 = *(const float4*)(kb + e0 + 4);
            int row = e0 >> 10, k = e0 & 1023;
            union { bf16x8 v; u16 u[8]; } p;
            p.u[0] = f2bf(v0.x); p.u[1] = f2bf(v0.y); p.u[2] = f2bf(v0.z); p.u[3] = f2bf(v0.w);
            p.u[4] = f2bf(v1.x); p.u[5] = f2bf(v1.y); p.u[6] = f2bf(v1.z); p.u[7] = f2bf(v1.w);
            int byte = (row * 2048 + k * 2) ^ ((row & 7) << 4);
            *(bf16x8*)(keysA + byte) = p.v;
        }
    }
    __syncthreads();

    const char* RpB = (const char*)Rp;
    const int arow  = h * 32 + l15;
    const int aswz  = (l15 & 7) << 4;

#pragma unroll 1
    for (int q = 0; q < 4; ++q) {
        const char* bb0 = RpB + (long long)((q * 16 + cs * 2 + 0) * 32) * 1024 + lam * 16;
        const char* bb1 = RpB + (long long)((q * 16 + cs * 2 + 1) * 32) * 1024 + lam * 16;

        f32x4 racc[2][2];
#pragma unroll
        for (int m = 0; m < 2; ++m) { racc[m][0] = (f32x4){0,0,0,0}; racc[m][1] = (f32x4){0,0,0,0}; }

        bf16x8 nbA0 = *(const bf16x8*)(bb0);
        bf16x8 nbA1 = *(const bf16x8*)(bb1);
        bf16x8 nbB0 = *(const bf16x8*)(bb0 + 1024);
        bf16x8 nbB1 = *(const bf16x8*)(bb1 + 1024);

#pragma unroll 4
        for (int ks = 0; ks < 32; ++ks) {
            bf16x8 cb0 = nbA0, cb1 = nbA1;
            nbA0 = nbB0; nbA1 = nbB1;
            if (ks < 30) {
                nbB0 = *(const bf16x8*)(bb0 + (ks + 2) * 1024);
                nbB1 = *(const bf16x8*)(bb1 + (ks + 2) * 1024);
            }
#pragma unroll
            for (int m = 0; m < 2; ++m) {
                int abyte = (((arow + m * 16) * 2048) + (ks * 32 + lg * 8) * 2) ^ aswz;
                bf16x8 a = *(const bf16x8*)(keysA + abyte);
                racc[m][0] = __builtin_amdgcn_mfma_f32_16x16x32_bf16(a, cb0, racc[m][0], 0, 0, 0);
                racc[m][1] = __builtin_amdgcn_mfma_f32_16x16x32_bf16(a, cb1, racc[m][1], 0, 0, 0);
            }
        }

        __syncthreads();
#pragma unroll
        for (int m = 0; m < 2; ++m)
#pragma unroll
            for (int n = 0; n < 2; ++n) {
                int qcol = cs * 32 + n * 16 + l15;
#pragma unroll
                for (int e = 0; e < 4; ++e) {
                    int key = h * 32 + m * 16 + lg * 4 + e;
                    int byte = key * 512 + ((((qcol >> 3) + 2 * key) & 31) << 4) + (qcol & 7) * 2;
                    *(u16*)(Krot + byte) = f2bf(racc[m][n][e]);
                }
            }
        __syncthreads();

        const int fmask = (q < 2) ? 0x80 : (q == 2) ? 0x88 : 0xA8;
        f32x4 acc[2][2];
#pragma unroll
        for (int m = 0; m < 2; ++m) { acc[m][0] = (f32x4){0,0,0,0}; acc[m][1] = (f32x4){0,0,0,0}; }
        float nrm[2] = {0.f, 0.f};
        int u = (q == 0) ? 0 : (q == 1) ? 1 : (q == 2) ? 2 : 4;

#pragma unroll
        for (int ks = 0; ks < 8; ++ks) {
            bf16x8 aq[2], bk[2];
            int cblk = q * 8 + ks;
#pragma unroll
            for (int m = 0; m < 2; ++m) {
                long long qoff = ((long long)(cblk * 16 + (cs * 2 + m)) * 64 + lam) * 8;
                aq[m] = *(const bf16x8*)(Qp + qoff);
            }
#pragma unroll
            for (int n = 0; n < 2; ++n) {
                int key = h * 32 + n * 16 + l15;
                int slot = ((ks * 4 + lg) + 2 * key) & 31;
                bk[n] = *(const bf16x8*)(Krot + key * 512 + (slot << 4));
            }
#pragma unroll
            for (int m = 0; m < 2; ++m)
#pragma unroll
                for (int n = 0; n < 2; ++n)
                    acc[m][n] = __builtin_amdgcn_mfma_f32_16x16x32_bf16(aq[m], bk[n], acc[m][n], 0, 0, 0);
#pragma unroll
            for (int n = 0; n < 2; ++n) {
                union { bf16x8 v; u16 s[8]; } ub; ub.v = bk[n];
#pragma unroll
                for (int j = 0; j < 8; ++j) { float f = bf2f(ub.s[j]); nrm[n] = fmaf(f, f, nrm[n]); }
            }

            if ((fmask >> ks) & 1) {
                float rn2[2];
#pragma unroll
                for (int n = 0; n < 2; ++n) {
                    float s = nrm[n];
                    s += __shfl_xor(s, 16);
                    s += __shfl_xor(s, 32);
                    rn2[n] = 1.0f / fmaxf(sqrtf(s), 1e-3f);
                    nrm[n] = 0.f;
                }
#pragma unroll
                for (int m = 0; m < 2; ++m) {
#pragma unroll
                    for (int e = 0; e < 4; ++e) {
                        float v0 = acc[m][0][e] * rn2[0];
                        float v1 = acc[m][1][e] * rn2[1];
                        float bv; int bi6;
                        if (v1 > v0) { bv = v1; bi6 = h * 32 + 16 + l15; }
                        else         { bv = v0; bi6 = h * 32 + l15; }
                        unsigned int ui = __float_as_uint(bv);
                        unsigned int mp = ui ^ (((int)ui < 0) ? 0xFFFFFFFFu : 0x80000000u);
                        unsigned int enc = (mp & 0xFFFFFFC0u) | (63u - (unsigned int)bi6);
#pragma unroll
                        for (int mask = 1; mask <= 8; mask <<= 1) {
                            unsigned int o = __shfl_xor(enc, mask);
                            enc = (o > enc) ? o : enc;
                        }
                        if (l15 == 0) {
                            int bi = 63 - (int)(enc & 63u);
                            unsigned int gl = (unsigned int)(row0 + bi);
                            unsigned long long e64 =
                                ((unsigned long long)(enc & 0xFFFFFFC0u) << 32) |
                                (unsigned long long)(0xFFFFFFFFu - gl);
                            int qq = cs * 32 + m * 16 + lg * 4 + e;
                            unsigned long long* addr = best + u * BZn + qq;
                            if (e64 > *addr) atomicMax(addr, e64);
                        }
                    }
#pragma unroll
                    for (int n = 0; n < 2; ++n) acc[m][n] = (f32x4){0,0,0,0};
                }
                ++u;
            }
        }
    }
}

// ---------------- finish: exact f32 cosine of the winners ----------------
__global__ void k_final(const float* __restrict__ keys, const float* __restrict__ R,
                        const float* __restrict__ Qrot,
                        const unsigned long long* __restrict__ best, float* __restrict__ out) {
    const int fid = blockIdx.x;
    const int u = fid >> 8, b = fid & 255;
    int off, d;
    if (u < 2)      { off = u * 256;            d = 256; }
    else if (u < 5) { off = 512 + (u - 2) * 128; d = 128; }
    else            { off = 896 + (u - 5) * 64;  d = 64;  }

    unsigned long long ent = best[fid];
    if (ent == 0ull) return;

    __shared__ float krow[Hd];
    __shared__ float red[12];
    const int t = threadIdx.x;
    unsigned int gl = 0xFFFFFFFFu - (unsigned int)(ent & 0xFFFFFFFFull);
    const float* kp = keys + (long long)gl * Hd;
    *(float4*)(&krow[t * 4]) = *(const float4*)(kp + t * 4);
    __syncthreads();

    float pn = 0.f, pq = 0.f, pk = 0.f;
    if (t < d) {
        float kr = 0.f;
        for (int k = 0; k < Hd; ++k) kr += krow[k] * R[(long long)k * Hd + off + t];
        float qv = Qrot[(long long)b * Hd + off + t];
        pn = qv * kr; pq = qv * qv; pk = kr * kr;
    }
    for (int mask = 1; mask <= 32; mask <<= 1) {
        pn += __shfl_xor(pn, mask); pq += __shfl_xor(pq, mask); pk += __shfl_xor(pk, mask);
    }
    if ((t & 63) == 0) { red[t >> 6] = pn; red[4 + (t >> 6)] = pq; red[8 + (t >> 6)] = pk; }
    __syncthreads();
    if (t == 0) {
        float nm = red[0] + red[1] + red[2] + red[3];
        float qq = red[4] + red[5] + red[6] + red[7];
        float kk = red[8] + red[9] + red[10] + red[11];
        float cosv = nm / (fmaxf(sqrtf(qq), 1e-8f) * fmaxf(sqrtf(kk), 1e-8f));
        atomicAdd(out, -cosv * (float)d / (256.0f * 1024.0f));
    }
}

// ---------------- launch ----------------
extern "C" void kernel_launch(void* const* d_in, const int* in_sizes, int n_in,
                              void* d_out, int out_size, void* d_ws, size_t ws_size,
                              hipStream_t stream) {
    (void)in_sizes; (void)n_in; (void)out_size;
    const float* query = (const float*)d_in[0];
    const float* keys  = (const float*)d_in[1];
    const float* R     = (const float*)d_in[2];
    float* out = (float*)d_out;
    char* ws = (char*)d_ws;

    unsigned long long* best = (unsigned long long*)ws;           // 16 KiB slot
    float* Qrot   = (float*)(ws + 16384);                         // 1 MiB
    u16*   Rpack  = (u16*)(ws + 16384 + 1048576);                 // 2 MiB
    u16*   Qpack  = (u16*)(ws + 16384 + 1048576 + 2097152);       // 512 KiB
    float* norms  = (float*)(ws + 3686400);                       // 4 MiB [key][8]
    u16*   rotK   = (u16*)(ws + 8388608);                         // 256 MiB

    const size_t WS_NEED = 8388608ull + (size_t)MTOT * Hd * 2;

    hipMemsetAsync(best, 0, NU * BZn * sizeof(unsigned long long), stream);
    hipMemsetAsync(out, 0, sizeof(float), stream);

    k_qrot <<<64,  256, 0, stream>>>(query, R, Qrot);
    k_rpack<<<512, 256, 0, stream>>>(R, Rpack);
    k_qpack<<<128, 256, 0, stream>>>(Qrot, Qpack);

    if (ws_size >= WS_NEED) {
        hipMemsetAsync(norms, 0, (size_t)MTOT * 8 * sizeof(float), stream);
        k_rot<<<8192, 256, 0, stream>>>(keys, Rpack, rotK, norms);
        k_sim<<<MTOT / 128, 512, 0, stream>>>(rotK, Qpack, norms, best);
    } else {
        hipFuncSetAttribute((const void*)k_main_fused,
                            hipFuncAttributeMaxDynamicSharedMemorySize, LDS_TOT_FB);
        k_main_fused<<<MTOT / 64, 1024, LDS_TOT_FB, stream>>>(keys, Rpack, Qpack, best);
    }
    k_final<<<NU * BZn, 256, 0, stream>>>(keys, R, Qrot, best, out);
}

// Round 9
// 1567.550 us; speedup vs baseline: 2.6746x; 2.6746x over previous
//
#include <hip/hip_runtime.h>
#include <hip/hip_bf16.h>
#include <stdint.h>

// ---------------- problem constants ----------------
static constexpr int Hd   = 1024;     // H_DIM
static constexpr int BZn  = 256;      // batch
static constexpr int MTOT = 131072;   // 32 * 4096 keys
static constexpr int NU   = 7;        // units

typedef float  f32x4  __attribute__((ext_vector_type(4)));
typedef short  bf16x8 __attribute__((ext_vector_type(8)));
typedef short  bf16x4 __attribute__((ext_vector_type(4)));
typedef unsigned short u16;

__device__ __forceinline__ u16 f2bf(float f) {
    __hip_bfloat16 h = __float2bfloat16(f);   // RNE
    return *reinterpret_cast<u16*>(&h);
}
__device__ __forceinline__ float bf2f(u16 h) {
    return __uint_as_float(((unsigned int)h) << 16);
}

// ---------------- prep kernels ----------------

// Qrot[256][1024] = query @ R  (f32). 64 blocks x 256.
__global__ void k_qrot(const float* __restrict__ query, const float* __restrict__ R,
                       float* __restrict__ Qrot) {
    __shared__ float qt[4][Hd];
    const int t = threadIdx.x;
    const int r0 = blockIdx.x * 4;
    for (int r = 0; r < 4; ++r)
        *(float4*)(&qt[r][t * 4]) = *(const float4*)(query + (long long)(r0 + r) * Hd + t * 4);
    __syncthreads();
    float acc[4][4] = {};
    for (int k = 0; k < Hd; ++k) {
        float4 rv = *(const float4*)(R + (long long)k * Hd + t * 4);
#pragma unroll
        for (int r = 0; r < 4; ++r) {
            float qv = qt[r][k];
            acc[r][0] += qv * rv.x; acc[r][1] += qv * rv.y;
            acc[r][2] += qv * rv.z; acc[r][3] += qv * rv.w;
        }
    }
    for (int r = 0; r < 4; ++r) {
        float4 o; o.x = acc[r][0]; o.y = acc[r][1]; o.z = acc[r][2]; o.w = acc[r][3];
        *(float4*)(Qrot + (long long)(r0 + r) * Hd + t * 4) = o;
    }
}

// Rpack: B-fragment layout for mfma_f32_16x16x32_bf16.
// frag id = (c0/16)*32 + (k0/32); lane l holds B[k0+(l>>4)*8+j][c0+(l&15)], j=0..7.
__global__ void k_rpack(const float* __restrict__ R, u16* __restrict__ Rpack) {
    const int gt = blockIdx.x * 256 + threadIdx.x;
    const int frag = gt >> 6, lam = gt & 63;
    const int cblk = frag >> 5, kblk = frag & 31;
    const int c  = cblk * 16 + (lam & 15);
    const int k0 = kblk * 32 + (lam >> 4) * 8;
    union { bf16x8 v; u16 u[8]; } p;
#pragma unroll
    for (int j = 0; j < 8; ++j) p.u[j] = f2bf(R[(long long)(k0 + j) * Hd + c]);
    *(bf16x8*)(Rpack + (long long)frag * 512 + lam * 8) = p.v;
}

// Qpack: A-fragment layout. frag id = (c0/32)*16 + (q0/16);
// lane l holds A[q0+(l&15)][c0+(l>>4)*8+j].
__global__ void k_qpack(const float* __restrict__ Qrot, u16* __restrict__ Qpack) {
    const int gt = blockIdx.x * 256 + threadIdx.x;
    const int frag = gt >> 6, lam = gt & 63;
    const int cblk = frag >> 4, qblk = frag & 15;
    const int q  = qblk * 16 + (lam & 15);
    const int c0 = cblk * 32 + (lam >> 4) * 8;
    union { bf16x8 v; u16 u[8]; } p;
#pragma unroll
    for (int j = 0; j < 8; ++j) p.u[j] = f2bf(Qrot[(long long)q * Hd + c0 + j]);
    *(bf16x8*)(Qpack + (long long)frag * 512 + lam * 8) = p.v;
}

// ---------------- GEMM 1: rotK = keys @ R (bf16 out) + unit norms ----------------
// 128x128 tile, 256 thr (4 waves), wave = 64keys x 64cols (4x4 frags), BK=32 dbuf.
// grid: bx = tkey*8 + cb -> the 8 col-blocks of a key-tile are CONSECUTIVE
// (temporal locality: L3 serves 7 of the 8 key-tile reads).
__global__ __launch_bounds__(256, 2)
void k_rot(const float* __restrict__ keys, const u16* __restrict__ Rp,
           u16* __restrict__ rotK, float* __restrict__ norms) {
    __shared__ char abuf[2][10240];     // [128 rows][80 B] per buf

    const int t   = threadIdx.x;
    const int lam = t & 63;
    const int w   = t >> 6;             // 4 waves
    const int l15 = lam & 15;
    const int lg  = lam >> 4;
    const int wq  = w >> 1;             // key half (64)
    const int wc  = w & 1;              // col half (64)

    const int bx   = blockIdx.x;
    const int tkey = bx >> 3;           // key-tile 0..1023
    const int cb   = bx & 7;            // col-block 0..7
    const int kb   = tkey * 128;

    // A staging: thread t loads row (t>>3), col bytes (t&7)*16 (128B/8rows per instr).
    const float* apt = keys + (long long)(kb + (t >> 3)) * Hd + (t & 7) * 4;
    const int sdst = (t >> 3) * 80 + (t & 7) * 8;

    // B-frag stream base: fid = (cb*8 + wc*4 + n)*32 + s
    const char* bB = (const char*)Rp + (long long)((cb * 8 + wc * 4) * 32) * 1024 + lam * 16;

    f32x4 acc[4][4];
#pragma unroll
    for (int m = 0; m < 4; ++m)
#pragma unroll
        for (int n = 0; n < 4; ++n) acc[m][n] = (f32x4){0.f, 0.f, 0.f, 0.f};

    // prologue prefetch (stage 0)
    float4 ar[4];
#pragma unroll
    for (int j = 0; j < 4; ++j) ar[j] = *(const float4*)(apt + (long long)j * 32 * Hd);
    bf16x8 nb[4];
#pragma unroll
    for (int n = 0; n < 4; ++n) nb[n] = *(const bf16x8*)(bB + (long long)(n * 32) * 1024);

#pragma unroll 2
    for (int s = 0; s < 32; ++s) {
        const int buf = s & 1;
        // convert + write staged A (4 x b64)
#pragma unroll
        for (int j = 0; j < 4; ++j) {
            union { bf16x4 v; u16 u[4]; } p;
            p.u[0] = f2bf(ar[j].x); p.u[1] = f2bf(ar[j].y);
            p.u[2] = f2bf(ar[j].z); p.u[3] = f2bf(ar[j].w);
            *(bf16x4*)(&abuf[buf][j * 2560 + sdst]) = p.v;
        }

        // prefetch next stage
        const int sn = (s < 31) ? s + 1 : 31;
#pragma unroll
        for (int j = 0; j < 4; ++j)
            ar[j] = *(const float4*)(apt + (long long)j * 32 * Hd + sn * 32);
        bf16x8 cbv[4];
#pragma unroll
        for (int n = 0; n < 4; ++n) cbv[n] = nb[n];
#pragma unroll
        for (int n = 0; n < 4; ++n)
            nb[n] = *(const bf16x8*)(bB + (long long)(n * 32 + sn) * 1024);

        __syncthreads();   // staged A visible

#pragma unroll
        for (int m = 0; m < 4; ++m) {
            int row = wq * 64 + m * 16 + l15;
            bf16x8 a = *(const bf16x8*)(&abuf[buf][row * 80 + lg * 16]);
#pragma unroll
            for (int n = 0; n < 4; ++n)
                acc[m][n] = __builtin_amdgcn_mfma_f32_16x16x32_bf16(a, cbv[n], acc[m][n], 0, 0, 0);
        }
    }

    // ---- per-(key,unit) sq-norm partials ----
    const int colbase = cb * 128 + wc * 64;
    const int c6 = colbase >> 6;
    const int u = (c6 < 4) ? 0 : (c6 < 8) ? 1 : (c6 < 10) ? 2 : (c6 < 12) ? 3
                : (c6 < 14) ? 4 : (c6 < 15) ? 5 : 6;
#pragma unroll
    for (int m = 0; m < 4; ++m) {
#pragma unroll
        for (int e = 0; e < 4; ++e) {
            const int key = kb + wq * 64 + m * 16 + lg * 4 + e;
            float s = 0.f;
#pragma unroll
            for (int n = 0; n < 4; ++n) { float v = acc[m][n][e]; s = fmaf(v, v, s); }
            s += __shfl_xor(s, 1); s += __shfl_xor(s, 2);
            s += __shfl_xor(s, 4); s += __shfl_xor(s, 8);
            if (l15 == 0) atomicAdd(norms + (long long)key * 8 + u, s);
        }
    }

    // ---- epilogue: LDS bounce -> coalesced rotK stores ----
    // FULLY UNROLLED m (rule #20: runtime-indexed acc => scratch; R8's 15 GB bug).
    // T = 32 rows x 128 cols bf16, stride 272 B.
    char* T = &abuf[0][0];
#pragma unroll
    for (int m = 0; m < 4; ++m) {
        __syncthreads();   // T free (prev m's reads / main loop's abuf[1] reads done)
#pragma unroll
        for (int n = 0; n < 4; ++n) {
            int tcol = wc * 64 + n * 16 + l15;
#pragma unroll
            for (int e = 0; e < 4; ++e) {
                int trow = wq * 16 + lg * 4 + e;
                *(u16*)(T + trow * 272 + tcol * 2) = f2bf(acc[m][n][e]);
            }
        }
        __syncthreads();   // T visible
#pragma unroll
        for (int p = 0; p < 2; ++p) {
            int row = p * 16 + (t >> 4);
            int colc = (t & 15) * 8;
            bf16x8 v = *(const bf16x8*)(T + row * 272 + colc * 2);
            int key = kb + (row >> 4) * 64 + m * 16 + (row & 15);
            *(bf16x8*)(rotK + (long long)key * Hd + cb * 128 + colc) = v;
        }
    }
}

// ---------------- GEMM 2: sims + segmented argmax ----------------
// block = 256 q x 64 keys, 256 thr (4 waves, wave = 64q x 64k). No LDS, no barriers.
// Depth-2 prefetch on rotK (long-latency), depth-1 on Qpack (L2-hot).
static constexpr unsigned int FMASK = 0xA8888080u;  // flush after ks 7,15,19,23,27,29,31

__global__ __launch_bounds__(256, 2)
void k_sim(const u16* __restrict__ rotK, const u16* __restrict__ Qp,
           const float* __restrict__ norms, unsigned long long* __restrict__ best) {
    const int t   = threadIdx.x;
    const int lam = t & 63;
    const int wq  = t >> 6;             // q quarter (64 queries)
    const int l15 = lam & 15;
    const int lg  = lam >> 4;
    const int key0 = blockIdx.x * 64;

    const char* QpB = (const char*)Qp;
    const char* KB  = (const char*)rotK;

    f32x4 acc[4][4];
#pragma unroll
    for (int m = 0; m < 4; ++m)
#pragma unroll
        for (int n = 0; n < 4; ++n) acc[m][n] = (f32x4){0.f, 0.f, 0.f, 0.f};

    // prefetch: bk depth-2, aq depth-1
    bf16x8 aqN[4], bkA[4], bkB[4];
#pragma unroll
    for (int m = 0; m < 4; ++m)
        aqN[m] = *(const bf16x8*)(QpB + (long long)(wq * 4 + m) * 1024 + lam * 16);
#pragma unroll
    for (int n = 0; n < 4; ++n) {
        bkA[n] = *(const bf16x8*)(KB + (long long)(key0 + n * 16 + l15) * 2048 + lg * 16);
        bkB[n] = *(const bf16x8*)(KB + (long long)(key0 + n * 16 + l15) * 2048 + 64 + lg * 16);
    }

#pragma unroll
    for (int ks = 0; ks < 32; ++ks) {
        bf16x8 aq[4], bk[4];
#pragma unroll
        for (int m = 0; m < 4; ++m) aq[m] = aqN[m];
#pragma unroll
        for (int n = 0; n < 4; ++n) { bk[n] = bkA[n]; bkA[n] = bkB[n]; }
        if (ks < 31) {
#pragma unroll
            for (int m = 0; m < 4; ++m)
                aqN[m] = *(const bf16x8*)(QpB + (long long)((ks + 1) * 16 + wq * 4 + m) * 1024 + lam * 16);
        }
        if (ks < 30) {
#pragma unroll
            for (int n = 0; n < 4; ++n)
                bkB[n] = *(const bf16x8*)(KB + (long long)(key0 + n * 16 + l15) * 2048 + (ks + 2) * 64 + lg * 16);
        }
#pragma unroll
        for (int m = 0; m < 4; ++m)
#pragma unroll
            for (int n = 0; n < 4; ++n)
                acc[m][n] = __builtin_amdgcn_mfma_f32_16x16x32_bf16(aq[m], bk[n], acc[m][n], 0, 0, 0);

        if ((FMASK >> ks) & 1) {
            const int u = __popc(FMASK & ((1u << ks) - 1u));
            float rn[4];
#pragma unroll
            for (int n = 0; n < 4; ++n) {
                float nv = norms[(long long)(key0 + n * 16 + l15) * 8 + u];
                rn[n] = 1.0f / fmaxf(sqrtf(nv), 1e-3f);
            }
#pragma unroll
            for (int m = 0; m < 4; ++m) {
#pragma unroll
                for (int e = 0; e < 4; ++e) {
                    float bv = acc[m][0][e] * rn[0];
                    int  bi6 = l15;
#pragma unroll
                    for (int n = 1; n < 4; ++n) {
                        float v = acc[m][n][e] * rn[n];
                        if (v > bv) { bv = v; bi6 = n * 16 + l15; }
                    }
                    unsigned int ui = __float_as_uint(bv);
                    unsigned int mp = ui ^ (((int)ui < 0) ? 0xFFFFFFFFu : 0x80000000u);
                    unsigned int enc = (mp & 0xFFFFFFC0u) | (63u - (unsigned int)bi6);
#pragma unroll
                    for (int mask = 1; mask <= 8; mask <<= 1) {
                        unsigned int o = __shfl_xor(enc, mask);
                        enc = (o > enc) ? o : enc;
                    }
                    if (l15 == 0) {
                        unsigned int gl = (unsigned int)(key0 + (63 - (int)(enc & 63u)));
                        unsigned long long e64 =
                            ((unsigned long long)(enc & 0xFFFFFFC0u) << 32) |
                            (unsigned long long)(0xFFFFFFFFu - gl);
                        int qq = wq * 64 + m * 16 + lg * 4 + e;
                        unsigned long long* addr = best + u * BZn + qq;
                        if (e64 > *addr) atomicMax(addr, e64);
                    }
#pragma unroll
                    for (int n = 0; n < 4; ++n) acc[m][n][e] = 0.f;
                }
            }
        }
    }
}

// ---------------- fallback fused kernel (R6) for small ws ----------------
static constexpr int LDS_TOT_FB = 163840;

__global__ __launch_bounds__(1024, 4)
void k_main_fused(const float* __restrict__ keys, const u16* __restrict__ Rp,
                  const u16* __restrict__ Qp, unsigned long long* __restrict__ best) {
    extern __shared__ char smem[];
    char* keysA = smem;
    char* Krot  = smem + 131072;

    const int t   = threadIdx.x;
    const int lam = t & 63;
    const int w   = t >> 6;
    const int l15 = lam & 15;
    const int lg  = lam >> 4;
    const int cs  = w >> 1;
    const int h   = w & 1;
    const int row0 = blockIdx.x * 64;

    {
        const float* kb = keys + (long long)row0 * Hd;
#pragma unroll
        for (int i = 0; i < 8; ++i) {
            int e0 = i * 8192 + t * 8;
            float4 v0 = *(const float4*)(kb + e0);
            float4 v1 = *(const float4*)(kb + e0 + 4);
            int row = e0 >> 10, k = e0 & 1023;
            union { bf16x8 v; u16 u[8]; } p;
            p.u[0] = f2bf(v0.x); p.u[1] = f2bf(v0.y); p.u[2] = f2bf(v0.z); p.u[3] = f2bf(v0.w);
            p.u[4] = f2bf(v1.x); p.u[5] = f2bf(v1.y); p.u[6] = f2bf(v1.z); p.u[7] = f2bf(v1.w);
            int byte = (row * 2048 + k * 2) ^ ((row & 7) << 4);
            *(bf16x8*)(keysA + byte) = p.v;
        }
    }
    __syncthreads();

    const char* RpB = (const char*)Rp;
    const int arow  = h * 32 + l15;
    const int aswz  = (l15 & 7) << 4;

#pragma unroll 1
    for (int q = 0; q < 4; ++q) {
        const char* bb0 = RpB + (long long)((q * 16 + cs * 2 + 0) * 32) * 1024 + lam * 16;
        const char* bb1 = RpB + (long long)((q * 16 + cs * 2 + 1) * 32) * 1024 + lam * 16;

        f32x4 racc[2][2];
#pragma unroll
        for (int m = 0; m < 2; ++m) { racc[m][0] = (f32x4){0,0,0,0}; racc[m][1] = (f32x4){0,0,0,0}; }

        bf16x8 nbA0 = *(const bf16x8*)(bb0);
        bf16x8 nbA1 = *(const bf16x8*)(bb1);
        bf16x8 nbB0 = *(const bf16x8*)(bb0 + 1024);
        bf16x8 nbB1 = *(const bf16x8*)(bb1 + 1024);

#pragma unroll 4
        for (int ks = 0; ks < 32; ++ks) {
            bf16x8 cb0 = nbA0, cb1 = nbA1;
            nbA0 = nbB0; nbA1 = nbB1;
            if (ks < 30) {
                nbB0 = *(const bf16x8*)(bb0 + (ks + 2) * 1024);
                nbB1 = *(const bf16x8*)(bb1 + (ks + 2) * 1024);
            }
#pragma unroll
            for (int m = 0; m < 2; ++m) {
                int abyte = (((arow + m * 16) * 2048) + (ks * 32 + lg * 8) * 2) ^ aswz;
                bf16x8 a = *(const bf16x8*)(keysA + abyte);
                racc[m][0] = __builtin_amdgcn_mfma_f32_16x16x32_bf16(a, cb0, racc[m][0], 0, 0, 0);
                racc[m][1] = __builtin_amdgcn_mfma_f32_16x16x32_bf16(a, cb1, racc[m][1], 0, 0, 0);
            }
        }

        __syncthreads();
#pragma unroll
        for (int m = 0; m < 2; ++m)
#pragma unroll
            for (int n = 0; n < 2; ++n) {
                int qcol = cs * 32 + n * 16 + l15;
#pragma unroll
                for (int e = 0; e < 4; ++e) {
                    int key = h * 32 + m * 16 + lg * 4 + e;
                    int byte = key * 512 + ((((qcol >> 3) + 2 * key) & 31) << 4) + (qcol & 7) * 2;
                    *(u16*)(Krot + byte) = f2bf(racc[m][n][e]);
                }
            }
        __syncthreads();

        const int fmask = (q < 2) ? 0x80 : (q == 2) ? 0x88 : 0xA8;
        f32x4 acc[2][2];
#pragma unroll
        for (int m = 0; m < 2; ++m) { acc[m][0] = (f32x4){0,0,0,0}; acc[m][1] = (f32x4){0,0,0,0}; }
        float nrm[2] = {0.f, 0.f};
        int u = (q == 0) ? 0 : (q == 1) ? 1 : (q == 2) ? 2 : 4;

#pragma unroll
        for (int ks = 0; ks < 8; ++ks) {
            bf16x8 aq[2], bk[2];
            int cblk = q * 8 + ks;
#pragma unroll
            for (int m = 0; m < 2; ++m) {
                long long qoff = ((long long)(cblk * 16 + (cs * 2 + m)) * 64 + lam) * 8;
                aq[m] = *(const bf16x8*)(Qp + qoff);
            }
#pragma unroll
            for (int n = 0; n < 2; ++n) {
                int key = h * 32 + n * 16 + l15;
                int slot = ((ks * 4 + lg) + 2 * key) & 31;
                bk[n] = *(const bf16x8*)(Krot + key * 512 + (slot << 4));
            }
#pragma unroll
            for (int m = 0; m < 2; ++m)
#pragma unroll
                for (int n = 0; n < 2; ++n)
                    acc[m][n] = __builtin_amdgcn_mfma_f32_16x16x32_bf16(aq[m], bk[n], acc[m][n], 0, 0, 0);
#pragma unroll
            for (int n = 0; n < 2; ++n) {
                union { bf16x8 v; u16 s[8]; } ub; ub.v = bk[n];
#pragma unroll
                for (int j = 0; j < 8; ++j) { float f = bf2f(ub.s[j]); nrm[n] = fmaf(f, f, nrm[n]); }
            }

            if ((fmask >> ks) & 1) {
                float rn2[2];
#pragma unroll
                for (int n = 0; n < 2; ++n) {
                    float s = nrm[n];
                    s += __shfl_xor(s, 16);
                    s += __shfl_xor(s, 32);
                    rn2[n] = 1.0f / fmaxf(sqrtf(s), 1e-3f);
                    nrm[n] = 0.f;
                }
#pragma unroll
                for (int m = 0; m < 2; ++m) {
#pragma unroll
                    for (int e = 0; e < 4; ++e) {
                        float v0 = acc[m][0][e] * rn2[0];
                        float v1 = acc[m][1][e] * rn2[1];
                        float bv; int bi6;
                        if (v1 > v0) { bv = v1; bi6 = h * 32 + 16 + l15; }
                        else         { bv = v0; bi6 = h * 32 + l15; }
                        unsigned int ui = __float_as_uint(bv);
                        unsigned int mp = ui ^ (((int)ui < 0) ? 0xFFFFFFFFu : 0x80000000u);
                        unsigned int enc = (mp & 0xFFFFFFC0u) | (63u - (unsigned int)bi6);
#pragma unroll
                        for (int mask = 1; mask <= 8; mask <<= 1) {
                            unsigned int o = __shfl_xor(enc, mask);
                            enc = (o > enc) ? o : enc;
                        }
                        if (l15 == 0) {
                            int bi = 63 - (int)(enc & 63u);
                            unsigned int gl = (unsigned int)(row0 + bi);
                            unsigned long long e64 =
                                ((unsigned long long)(enc & 0xFFFFFFC0u) << 32) |
                                (unsigned long long)(0xFFFFFFFFu - gl);
                            int qq = cs * 32 + m * 16 + lg * 4 + e;
                            unsigned long long* addr = best + u * BZn + qq;
                            if (e64 > *addr) atomicMax(addr, e64);
                        }
                    }
#pragma unroll
                    for (int n = 0; n < 2; ++n) acc[m][n] = (f32x4){0,0,0,0};
                }
                ++u;
            }
        }
    }
}

// ---------------- finish: exact f32 cosine of the winners ----------------
__global__ void k_final(const float* __restrict__ keys, const float* __restrict__ R,
                        const float* __restrict__ Qrot,
                        const unsigned long long* __restrict__ best, float* __restrict__ out) {
    const int fid = blockIdx.x;
    const int u = fid >> 8, b = fid & 255;
    int off, d;
    if (u < 2)      { off = u * 256;            d = 256; }
    else if (u < 5) { off = 512 + (u - 2) * 128; d = 128; }
    else            { off = 896 + (u - 5) * 64;  d = 64;  }

    unsigned long long ent = best[fid];
    if (ent == 0ull) return;

    __shared__ float krow[Hd];
    __shared__ float red[12];
    const int t = threadIdx.x;
    unsigned int gl = 0xFFFFFFFFu - (unsigned int)(ent & 0xFFFFFFFFull);
    const float* kp = keys + (long long)gl * Hd;
    *(float4*)(&krow[t * 4]) = *(const float4*)(kp + t * 4);
    __syncthreads();

    float pn = 0.f, pq = 0.f, pk = 0.f;
    if (t < d) {
        float kr = 0.f;
        for (int k = 0; k < Hd; ++k) kr += krow[k] * R[(long long)k * Hd + off + t];
        float qv = Qrot[(long long)b * Hd + off + t];
        pn = qv * kr; pq = qv * qv; pk = kr * kr;
    }
    for (int mask = 1; mask <= 32; mask <<= 1) {
        pn += __shfl_xor(pn, mask); pq += __shfl_xor(pq, mask); pk += __shfl_xor(pk, mask);
    }
    if ((t & 63) == 0) { red[t >> 6] = pn; red[4 + (t >> 6)] = pq; red[8 + (t >> 6)] = pk; }
    __syncthreads();
    if (t == 0) {
        float nm = red[0] + red[1] + red[2] + red[3];
        float qq = red[4] + red[5] + red[6] + red[7];
        float kk = red[8] + red[9] + red[10] + red[11];
        float cosv = nm / (fmaxf(sqrtf(qq), 1e-8f) * fmaxf(sqrtf(kk), 1e-8f));
        atomicAdd(out, -cosv * (float)d / (256.0f * 1024.0f));
    }
}

// ---------------- launch ----------------
extern "C" void kernel_launch(void* const* d_in, const int* in_sizes, int n_in,
                              void* d_out, int out_size, void* d_ws, size_t ws_size,
                              hipStream_t stream) {
    (void)in_sizes; (void)n_in; (void)out_size;
    const float* query = (const float*)d_in[0];
    const float* keys  = (const float*)d_in[1];
    const float* R     = (const float*)d_in[2];
    float* out = (float*)d_out;
    char* ws = (char*)d_ws;

    unsigned long long* best = (unsigned long long*)ws;           // 16 KiB slot
    float* Qrot   = (float*)(ws + 16384);                         // 1 MiB
    u16*   Rpack  = (u16*)(ws + 16384 + 1048576);                 // 2 MiB
    u16*   Qpack  = (u16*)(ws + 16384 + 1048576 + 2097152);       // 512 KiB
    float* norms  = (float*)(ws + 3686400);                       // 4 MiB [key][8]
    u16*   rotK   = (u16*)(ws + 8388608);                         // 256 MiB

    const size_t WS_NEED = 8388608ull + (size_t)MTOT * Hd * 2;

    hipMemsetAsync(best, 0, NU * BZn * sizeof(unsigned long long), stream);
    hipMemsetAsync(out, 0, sizeof(float), stream);

    k_qrot <<<64,  256, 0, stream>>>(query, R, Qrot);
    k_rpack<<<512, 256, 0, stream>>>(R, Rpack);
    k_qpack<<<128, 256, 0, stream>>>(Qrot, Qpack);

    if (ws_size >= WS_NEED) {
        hipMemsetAsync(norms, 0, (size_t)MTOT * 8 * sizeof(float), stream);
        k_rot<<<8192, 256, 0, stream>>>(keys, Rpack, rotK, norms);
        k_sim<<<MTOT / 64, 256, 0, stream>>>(rotK, Qpack, norms, best);
    } else {
        hipFuncSetAttribute((const void*)k_main_fused,
                            hipFuncAttributeMaxDynamicSharedMemorySize, LDS_TOT_FB);
        k_main_fused<<<MTOT / 64, 1024, LDS_TOT_FB, stream>>>(keys, Rpack, Qpack, best);
    }
    k_final<<<NU * BZn, 256, 0, stream>>>(keys, R, Qrot, best, out);
}

// Round 10
// 1516.672 us; speedup vs baseline: 2.7644x; 1.0335x over previous
//
#include <hip/hip_runtime.h>
#include <hip/hip_bf16.h>
#include <stdint.h>

// ---------------- problem constants ----------------
static constexpr int Hd   = 1024;     // H_DIM
static constexpr int BZn  = 256;      // batch
static constexpr int MTOT = 131072;   // 32 * 4096 keys
static constexpr int NU   = 7;        // units

typedef float  f32x4  __attribute__((ext_vector_type(4)));
typedef short  bf16x8 __attribute__((ext_vector_type(8)));
typedef short  bf16x4 __attribute__((ext_vector_type(4)));
typedef unsigned short u16;

__device__ __forceinline__ u16 f2bf(float f) {
    __hip_bfloat16 h = __float2bfloat16(f);   // RNE
    return *reinterpret_cast<u16*>(&h);
}

// ---------------- prep kernels ----------------

// Qrot[256][1024] = query @ R  (f32). 64 blocks x 256.
__global__ void k_qrot(const float* __restrict__ query, const float* __restrict__ R,
                       float* __restrict__ Qrot) {
    __shared__ float qt[4][Hd];
    const int t = threadIdx.x;
    const int r0 = blockIdx.x * 4;
    for (int r = 0; r < 4; ++r)
        *(float4*)(&qt[r][t * 4]) = *(const float4*)(query + (long long)(r0 + r) * Hd + t * 4);
    __syncthreads();
    float acc[4][4] = {};
    for (int k = 0; k < Hd; ++k) {
        float4 rv = *(const float4*)(R + (long long)k * Hd + t * 4);
#pragma unroll
        for (int r = 0; r < 4; ++r) {
            float qv = qt[r][k];
            acc[r][0] += qv * rv.x; acc[r][1] += qv * rv.y;
            acc[r][2] += qv * rv.z; acc[r][3] += qv * rv.w;
        }
    }
    for (int r = 0; r < 4; ++r) {
        float4 o; o.x = acc[r][0]; o.y = acc[r][1]; o.z = acc[r][2]; o.w = acc[r][3];
        *(float4*)(Qrot + (long long)(r0 + r) * Hd + t * 4) = o;
    }
}

// Rpack: B-fragment layout for mfma_f32_16x16x32_bf16.
// frag id = (c0/16)*32 + (k0/32); lane l holds B[k0+(l>>4)*8+j][c0+(l&15)], j=0..7.
__global__ void k_rpack(const float* __restrict__ R, u16* __restrict__ Rpack) {
    const int gt = blockIdx.x * 256 + threadIdx.x;
    const int frag = gt >> 6, lam = gt & 63;
    const int cblk = frag >> 5, kblk = frag & 31;
    const int c  = cblk * 16 + (lam & 15);
    const int k0 = kblk * 32 + (lam >> 4) * 8;
    union { bf16x8 v; u16 u[8]; } p;
#pragma unroll
    for (int j = 0; j < 8; ++j) p.u[j] = f2bf(R[(long long)(k0 + j) * Hd + c]);
    *(bf16x8*)(Rpack + (long long)frag * 512 + lam * 8) = p.v;
}

// Qpack: A-fragment layout. frag id = (c0/32)*16 + (q0/16);
// lane l holds A[q0+(l&15)][c0+(l>>4)*8+j].
__global__ void k_qpack(const float* __restrict__ Qrot, u16* __restrict__ Qpack) {
    const int gt = blockIdx.x * 256 + threadIdx.x;
    const int frag = gt >> 6, lam = gt & 63;
    const int cblk = frag >> 4, qblk = frag & 15;
    const int q  = qblk * 16 + (lam & 15);
    const int c0 = cblk * 32 + (lam >> 4) * 8;
    union { bf16x8 v; u16 u[8]; } p;
#pragma unroll
    for (int j = 0; j < 8; ++j) p.u[j] = f2bf(Qrot[(long long)q * Hd + c0 + j]);
    *(bf16x8*)(Qpack + (long long)frag * 512 + lam * 8) = p.v;
}

// ---------------- GEMM 1: rotKf = frag-layout(keys @ R) + unit norms ----------------
// 128x128 tile, 256 thr (4 waves), wave = 64keys x 64cols (4x4 frags), BK=32 dbuf.
// grid: bx = tkey*8 + cb (col-blocks of a key-tile consecutive -> L3 temporal reuse).
// Output rotKf: B-frag layout for k_sim. frag id = kblk*32 + cstep (kblk=key/16,
// cstep=col/32); lane l holds rot[key=16*kblk+(l&15)][col=cstep*32+(l>>4)*8+j].
// norms layout: [u][key] (contiguous key reads in k_sim).
__global__ __launch_bounds__(256, 2)
void k_rot(const float* __restrict__ keys, const u16* __restrict__ Rp,
           u16* __restrict__ rotKf, float* __restrict__ norms) {
    __shared__ char abuf[2][10240];     // [128 rows][80 B] per buf

    const int t   = threadIdx.x;
    const int lam = t & 63;
    const int w   = t >> 6;             // 4 waves
    const int l15 = lam & 15;
    const int lg  = lam >> 4;
    const int wq  = w >> 1;             // key half (64)
    const int wc  = w & 1;              // col half (64)

    const int bx   = blockIdx.x;
    const int tkey = bx >> 3;           // key-tile 0..1023
    const int cb   = bx & 7;            // col-block 0..7
    const int kb   = tkey * 128;

    // A staging: thread t loads row (t>>3), 16B at col (t&7)*4.
    const float* apt = keys + (long long)(kb + (t >> 3)) * Hd + (t & 7) * 4;
    const int sdst = (t >> 3) * 80 + (t & 7) * 8;

    // B-frag stream base: fid = (cb*8 + wc*4 + n)*32 + s
    const char* bB = (const char*)Rp + (long long)((cb * 8 + wc * 4) * 32) * 1024 + lam * 16;

    f32x4 acc[4][4];
#pragma unroll
    for (int m = 0; m < 4; ++m)
#pragma unroll
        for (int n = 0; n < 4; ++n) acc[m][n] = (f32x4){0.f, 0.f, 0.f, 0.f};

    // prologue prefetch (stage 0)
    float4 ar[4];
#pragma unroll
    for (int j = 0; j < 4; ++j) ar[j] = *(const float4*)(apt + (long long)j * 32 * Hd);
    bf16x8 nb[4];
#pragma unroll
    for (int n = 0; n < 4; ++n) nb[n] = *(const bf16x8*)(bB + (long long)(n * 32) * 1024);

#pragma unroll 2
    for (int s = 0; s < 32; ++s) {
        const int buf = s & 1;
        // convert + write staged A (4 x b64)
#pragma unroll
        for (int j = 0; j < 4; ++j) {
            union { bf16x4 v; u16 u[4]; } p;
            p.u[0] = f2bf(ar[j].x); p.u[1] = f2bf(ar[j].y);
            p.u[2] = f2bf(ar[j].z); p.u[3] = f2bf(ar[j].w);
            *(bf16x4*)(&abuf[buf][j * 2560 + sdst]) = p.v;
        }

        // prefetch next stage
        const int sn = (s < 31) ? s + 1 : 31;
#pragma unroll
        for (int j = 0; j < 4; ++j)
            ar[j] = *(const float4*)(apt + (long long)j * 32 * Hd + sn * 32);
        bf16x8 cbv[4];
#pragma unroll
        for (int n = 0; n < 4; ++n) cbv[n] = nb[n];
#pragma unroll
        for (int n = 0; n < 4; ++n)
            nb[n] = *(const bf16x8*)(bB + (long long)(n * 32 + sn) * 1024);

        __syncthreads();   // staged A visible

#pragma unroll
        for (int m = 0; m < 4; ++m) {
            int row = wq * 64 + m * 16 + l15;
            bf16x8 a = *(const bf16x8*)(&abuf[buf][row * 80 + lg * 16]);
#pragma unroll
            for (int n = 0; n < 4; ++n)
                acc[m][n] = __builtin_amdgcn_mfma_f32_16x16x32_bf16(a, cbv[n], acc[m][n], 0, 0, 0);
        }
    }

    // ---- per-(key,unit) sq-norm partials, norms layout [u][key] ----
    const int colbase = cb * 128 + wc * 64;
    const int c6 = colbase >> 6;
    const int u = (c6 < 4) ? 0 : (c6 < 8) ? 1 : (c6 < 10) ? 2 : (c6 < 12) ? 3
                : (c6 < 14) ? 4 : (c6 < 15) ? 5 : 6;
#pragma unroll
    for (int m = 0; m < 4; ++m) {
#pragma unroll
        for (int e = 0; e < 4; ++e) {
            const int key = kb + wq * 64 + m * 16 + lg * 4 + e;
            float s = 0.f;
#pragma unroll
            for (int n = 0; n < 4; ++n) { float v = acc[m][n][e]; s = fmaf(v, v, s); }
            s += __shfl_xor(s, 1); s += __shfl_xor(s, 2);
            s += __shfl_xor(s, 4); s += __shfl_xor(s, 8);
            if (l15 == 0) atomicAdd(norms + (long long)u * MTOT + key, s);
        }
    }

    // ---- epilogue: LDS bounce -> B-frag-layout stores (fully unrolled: rule #20) ----
    // T = 32 keys x 128 cols bf16, stride 272 B.
    char* T = &abuf[0][0];
#pragma unroll
    for (int m = 0; m < 4; ++m) {
        __syncthreads();   // T free
#pragma unroll
        for (int n = 0; n < 4; ++n) {
            int tcol = wc * 64 + n * 16 + l15;
#pragma unroll
            for (int e = 0; e < 4; ++e) {
                int trow = wq * 16 + lg * 4 + e;
                *(u16*)(T + trow * 272 + tcol * 2) = f2bf(acc[m][n][e]);
            }
        }
        __syncthreads();   // T visible
        // extract 8 frags (kb2 0..1 x cl 0..3); wave w does frags w and w+4.
#pragma unroll
        for (int p = 0; p < 2; ++p) {
            int fi  = p * 4 + w;
            int kb2 = fi >> 2;           // 0..1
            int cl  = fi & 3;            // 0..3
            int trow = kb2 * 16 + l15;
            bf16x8 v = *(const bf16x8*)(T + trow * 272 + cl * 64 + lg * 16);
            int gkblk  = (kb >> 4) + kb2 * 4 + m;   // key/16
            int gcstep = cb * 4 + cl;               // col/32
            *(bf16x8*)(rotKf + (long long)(gkblk * 32 + gcstep) * 512 + lam * 8) = v;
        }
    }
}

// ---------------- GEMM 2: sims + segmented argmax ----------------
// block = 256 q x 64 keys, 256 thr (4 waves = 4 q-quarters). No LDS, no barriers.
// All streams CONTIGUOUS (rotKf frag layout). bk depth-2, aq depth-1 prefetch.
static constexpr unsigned int FMASK = 0xA8888080u;  // flush after ks 7,15,19,23,27,29,31

__global__ __launch_bounds__(256, 2)
void k_sim(const u16* __restrict__ rotKf, const u16* __restrict__ Qp,
           const float* __restrict__ norms, unsigned long long* __restrict__ best) {
    const int t   = threadIdx.x;
    const int lam = t & 63;
    const int wq  = t >> 6;             // q quarter (64 queries)
    const int l15 = lam & 15;
    const int lg  = lam >> 4;
    const int key0  = blockIdx.x * 64;
    const int kblk0 = blockIdx.x * 4;   // key/16 base

    const char* QpB = (const char*)Qp;
    const char* KF  = (const char*)rotKf;

    f32x4 acc[4][4];
#pragma unroll
    for (int m = 0; m < 4; ++m)
#pragma unroll
        for (int n = 0; n < 4; ++n) acc[m][n] = (f32x4){0.f, 0.f, 0.f, 0.f};

    // prefetch: bk depth-2, aq depth-1 (all contiguous 1KB wave-loads)
    bf16x8 aqN[4], bkA[4], bkB[4];
#pragma unroll
    for (int m = 0; m < 4; ++m)
        aqN[m] = *(const bf16x8*)(QpB + (long long)(wq * 4 + m) * 1024 + lam * 16);
#pragma unroll
    for (int n = 0; n < 4; ++n) {
        bkA[n] = *(const bf16x8*)(KF + (long long)((kblk0 + n) * 32 + 0) * 1024 + lam * 16);
        bkB[n] = *(const bf16x8*)(KF + (long long)((kblk0 + n) * 32 + 1) * 1024 + lam * 16);
    }

#pragma unroll
    for (int ks = 0; ks < 32; ++ks) {
        bf16x8 aq[4], bk[4];
#pragma unroll
        for (int m = 0; m < 4; ++m) aq[m] = aqN[m];
#pragma unroll
        for (int n = 0; n < 4; ++n) { bk[n] = bkA[n]; bkA[n] = bkB[n]; }
        if (ks < 31) {
#pragma unroll
            for (int m = 0; m < 4; ++m)
                aqN[m] = *(const bf16x8*)(QpB + (long long)((ks + 1) * 16 + wq * 4 + m) * 1024 + lam * 16);
        }
        if (ks < 30) {
#pragma unroll
            for (int n = 0; n < 4; ++n)
                bkB[n] = *(const bf16x8*)(KF + (long long)((kblk0 + n) * 32 + ks + 2) * 1024 + lam * 16);
        }
#pragma unroll
        for (int m = 0; m < 4; ++m)
#pragma unroll
            for (int n = 0; n < 4; ++n)
                acc[m][n] = __builtin_amdgcn_mfma_f32_16x16x32_bf16(aq[m], bk[n], acc[m][n], 0, 0, 0);

        if ((FMASK >> ks) & 1) {
            const int u = __popc(FMASK & ((1u << ks) - 1u));
            float rn[4];
#pragma unroll
            for (int n = 0; n < 4; ++n) {
                float nv = norms[(long long)u * MTOT + key0 + n * 16 + l15];
                rn[n] = 1.0f / fmaxf(sqrtf(nv), 1e-3f);
            }
#pragma unroll
            for (int m = 0; m < 4; ++m) {
#pragma unroll
                for (int e = 0; e < 4; ++e) {
                    float bv = acc[m][0][e] * rn[0];
                    int  bi6 = l15;
#pragma unroll
                    for (int n = 1; n < 4; ++n) {
                        float v = acc[m][n][e] * rn[n];
                        if (v > bv) { bv = v; bi6 = n * 16 + l15; }
                    }
                    unsigned int ui = __float_as_uint(bv);
                    unsigned int mp = ui ^ (((int)ui < 0) ? 0xFFFFFFFFu : 0x80000000u);
                    unsigned int enc = (mp & 0xFFFFFFC0u) | (63u - (unsigned int)bi6);
#pragma unroll
                    for (int mask = 1; mask <= 8; mask <<= 1) {
                        unsigned int o = __shfl_xor(enc, mask);
                        enc = (o > enc) ? o : enc;
                    }
                    if (l15 == 0) {
                        unsigned int gl = (unsigned int)(key0 + (63 - (int)(enc & 63u)));
                        unsigned long long e64 =
                            ((unsigned long long)(enc & 0xFFFFFFC0u) << 32) |
                            (unsigned long long)(0xFFFFFFFFu - gl);
                        int qq = wq * 64 + m * 16 + lg * 4 + e;
                        unsigned long long* addr = best + u * BZn + qq;
                        if (e64 > *addr) atomicMax(addr, e64);
                    }
#pragma unroll
                    for (int n = 0; n < 4; ++n) acc[m][n][e] = 0.f;
                }
            }
        }
    }
}

// ---------------- fallback fused kernel (R6) for small ws ----------------
static constexpr int LDS_TOT_FB = 163840;

__global__ __launch_bounds__(1024, 4)
void k_main_fused(const float* __restrict__ keys, const u16* __restrict__ Rp,
                  const u16* __restrict__ Qp, unsigned long long* __restrict__ best) {
    extern __shared__ char smem[];
    char* keysA = smem;
    char* Krot  = smem + 131072;

    const int t   = threadIdx.x;
    const int lam = t & 63;
    const int w   = t >> 6;
    const int l15 = lam & 15;
    const int lg  = lam >> 4;
    const int cs  = w >> 1;
    const int h   = w & 1;
    const int row0 = blockIdx.x * 64;

    {
        const float* kb = keys + (long long)row0 * Hd;
#pragma unroll
        for (int i = 0; i < 8; ++i) {
            int e0 = i * 8192 + t * 8;
            float4 v0 = *(const float4*)(kb + e0);
            float4 v1 = *(const float4*)(kb + e0 + 4);
            int row = e0 >> 10, k = e0 & 1023;
            union { bf16x8 v; u16 u[8]; } p;
            p.u[0] = f2bf(v0.x); p.u[1] = f2bf(v0.y); p.u[2] = f2bf(v0.z); p.u[3] = f2bf(v0.w);
            p.u[4] = f2bf(v1.x); p.u[5] = f2bf(v1.y); p.u[6] = f2bf(v1.z); p.u[7] = f2bf(v1.w);
            int byte = (row * 2048 + k * 2) ^ ((row & 7) << 4);
            *(bf16x8*)(keysA + byte) = p.v;
        }
    }
    __syncthreads();

    const char* RpB = (const char*)Rp;
    const int arow  = h * 32 + l15;
    const int aswz  = (l15 & 7) << 4;

#pragma unroll 1
    for (int q = 0; q < 4; ++q) {
        const char* bb0 = RpB + (long long)((q * 16 + cs * 2 + 0) * 32) * 1024 + lam * 16;
        const char* bb1 = RpB + (long long)((q * 16 + cs * 2 + 1) * 32) * 1024 + lam * 16;

        f32x4 racc[2][2];
#pragma unroll
        for (int m = 0; m < 2; ++m) { racc[m][0] = (f32x4){0,0,0,0}; racc[m][1] = (f32x4){0,0,0,0}; }

        bf16x8 nbA0 = *(const bf16x8*)(bb0);
        bf16x8 nbA1 = *(const bf16x8*)(bb1);
        bf16x8 nbB0 = *(const bf16x8*)(bb0 + 1024);
        bf16x8 nbB1 = *(const bf16x8*)(bb1 + 1024);

#pragma unroll 4
        for (int ks = 0; ks < 32; ++ks) {
            bf16x8 cb0 = nbA0, cb1 = nbA1;
            nbA0 = nbB0; nbA1 = nbB1;
            if (ks < 30) {
                nbB0 = *(const bf16x8*)(bb0 + (ks + 2) * 1024);
                nbB1 = *(const bf16x8*)(bb1 + (ks + 2) * 1024);
            }
#pragma unroll
            for (int m = 0; m < 2; ++m) {
                int abyte = (((arow + m * 16) * 2048) + (ks * 32 + lg * 8) * 2) ^ aswz;
                bf16x8 a = *(const bf16x8*)(keysA + abyte);
                racc[m][0] = __builtin_amdgcn_mfma_f32_16x16x32_bf16(a, cb0, racc[m][0], 0, 0, 0);
                racc[m][1] = __builtin_amdgcn_mfma_f32_16x16x32_bf16(a, cb1, racc[m][1], 0, 0, 0);
            }
        }

        __syncthreads();
#pragma unroll
        for (int m = 0; m < 2; ++m)
#pragma unroll
            for (int n = 0; n < 2; ++n) {
                int qcol = cs * 32 + n * 16 + l15;
#pragma unroll
                for (int e = 0; e < 4; ++e) {
                    int key = h * 32 + m * 16 + lg * 4 + e;
                    int byte = key * 512 + ((((qcol >> 3) + 2 * key) & 31) << 4) + (qcol & 7) * 2;
                    *(u16*)(Krot + byte) = f2bf(racc[m][n][e]);
                }
            }
        __syncthreads();

        const int fmask = (q < 2) ? 0x80 : (q == 2) ? 0x88 : 0xA8;
        f32x4 acc[2][2];
#pragma unroll
        for (int m = 0; m < 2; ++m) { acc[m][0] = (f32x4){0,0,0,0}; acc[m][1] = (f32x4){0,0,0,0}; }
        float nrm[2] = {0.f, 0.f};
        int u = (q == 0) ? 0 : (q == 1) ? 1 : (q == 2) ? 2 : 4;

#pragma unroll
        for (int ks = 0; ks < 8; ++ks) {
            bf16x8 aq[2], bk[2];
            int cblk = q * 8 + ks;
#pragma unroll
            for (int m = 0; m < 2; ++m) {
                long long qoff = ((long long)(cblk * 16 + (cs * 2 + m)) * 64 + lam) * 8;
                aq[m] = *(const bf16x8*)(Qp + qoff);
            }
#pragma unroll
            for (int n = 0; n < 2; ++n) {
                int key = h * 32 + n * 16 + l15;
                int slot = ((ks * 4 + lg) + 2 * key) & 31;
                bk[n] = *(const bf16x8*)(Krot + key * 512 + (slot << 4));
            }
#pragma unroll
            for (int m = 0; m < 2; ++m)
#pragma unroll
                for (int n = 0; n < 2; ++n)
                    acc[m][n] = __builtin_amdgcn_mfma_f32_16x16x32_bf16(aq[m], bk[n], acc[m][n], 0, 0, 0);
#pragma unroll
            for (int n = 0; n < 2; ++n) {
                union { bf16x8 v; u16 s[8]; } ub; ub.v = bk[n];
#pragma unroll
                for (int j = 0; j < 8; ++j) {
                    float f = __uint_as_float(((unsigned int)ub.s[j]) << 16);
                    nrm[n] = fmaf(f, f, nrm[n]);
                }
            }

            if ((fmask >> ks) & 1) {
                float rn2[2];
#pragma unroll
                for (int n = 0; n < 2; ++n) {
                    float s = nrm[n];
                    s += __shfl_xor(s, 16);
                    s += __shfl_xor(s, 32);
                    rn2[n] = 1.0f / fmaxf(sqrtf(s), 1e-3f);
                    nrm[n] = 0.f;
                }
#pragma unroll
                for (int m = 0; m < 2; ++m) {
#pragma unroll
                    for (int e = 0; e < 4; ++e) {
                        float v0 = acc[m][0][e] * rn2[0];
                        float v1 = acc[m][1][e] * rn2[1];
                        float bv; int bi6;
                        if (v1 > v0) { bv = v1; bi6 = h * 32 + 16 + l15; }
                        else         { bv = v0; bi6 = h * 32 + l15; }
                        unsigned int ui = __float_as_uint(bv);
                        unsigned int mp = ui ^ (((int)ui < 0) ? 0xFFFFFFFFu : 0x80000000u);
                        unsigned int enc = (mp & 0xFFFFFFC0u) | (63u - (unsigned int)bi6);
#pragma unroll
                        for (int mask = 1; mask <= 8; mask <<= 1) {
                            unsigned int o = __shfl_xor(enc, mask);
                            enc = (o > enc) ? o : enc;
                        }
                        if (l15 == 0) {
                            int bi = 63 - (int)(enc & 63u);
                            unsigned int gl = (unsigned int)(row0 + bi);
                            unsigned long long e64 =
                                ((unsigned long long)(enc & 0xFFFFFFC0u) << 32) |
                                (unsigned long long)(0xFFFFFFFFu - gl);
                            int qq = cs * 32 + m * 16 + lg * 4 + e;
                            unsigned long long* addr = best + u * BZn + qq;
                            if (e64 > *addr) atomicMax(addr, e64);
                        }
                    }
#pragma unroll
                    for (int n = 0; n < 2; ++n) acc[m][n] = (f32x4){0,0,0,0};
                }
                ++u;
            }
        }
    }
}

// ---------------- finish: exact f32 cosine of the winners ----------------
__global__ void k_final(const float* __restrict__ keys, const float* __restrict__ R,
                        const float* __restrict__ Qrot,
                        const unsigned long long* __restrict__ best, float* __restrict__ out) {
    const int fid = blockIdx.x;
    const int u = fid >> 8, b = fid & 255;
    int off, d;
    if (u < 2)      { off = u * 256;            d = 256; }
    else if (u < 5) { off = 512 + (u - 2) * 128; d = 128; }
    else            { off = 896 + (u - 5) * 64;  d = 64;  }

    unsigned long long ent = best[fid];
    if (ent == 0ull) return;

    __shared__ float krow[Hd];
    __shared__ float red[12];
    const int t = threadIdx.x;
    unsigned int gl = 0xFFFFFFFFu - (unsigned int)(ent & 0xFFFFFFFFull);
    const float* kp = keys + (long long)gl * Hd;
    *(float4*)(&krow[t * 4]) = *(const float4*)(kp + t * 4);
    __syncthreads();

    float pn = 0.f, pq = 0.f, pk = 0.f;
    if (t < d) {
        float kr = 0.f;
        for (int k = 0; k < Hd; ++k) kr += krow[k] * R[(long long)k * Hd + off + t];
        float qv = Qrot[(long long)b * Hd + off + t];
        pn = qv * kr; pq = qv * qv; pk = kr * kr;
    }
    for (int mask = 1; mask <= 32; mask <<= 1) {
        pn += __shfl_xor(pn, mask); pq += __shfl_xor(pq, mask); pk += __shfl_xor(pk, mask);
    }
    if ((t & 63) == 0) { red[t >> 6] = pn; red[4 + (t >> 6)] = pq; red[8 + (t >> 6)] = pk; }
    __syncthreads();
    if (t == 0) {
        float nm = red[0] + red[1] + red[2] + red[3];
        float qq = red[4] + red[5] + red[6] + red[7];
        float kk = red[8] + red[9] + red[10] + red[11];
        float cosv = nm / (fmaxf(sqrtf(qq), 1e-8f) * fmaxf(sqrtf(kk), 1e-8f));
        atomicAdd(out, -cosv * (float)d / (256.0f * 1024.0f));
    }
}

// ---------------- launch ----------------
extern "C" void kernel_launch(void* const* d_in, const int* in_sizes, int n_in,
                              void* d_out, int out_size, void* d_ws, size_t ws_size,
                              hipStream_t stream) {
    (void)in_sizes; (void)n_in; (void)out_size;
    const float* query = (const float*)d_in[0];
    const float* keys  = (const float*)d_in[1];
    const float* R     = (const float*)d_in[2];
    float* out = (float*)d_out;
    char* ws = (char*)d_ws;

    unsigned long long* best = (unsigned long long*)ws;           // 16 KiB slot
    float* Qrot   = (float*)(ws + 16384);                         // 1 MiB
    u16*   Rpack  = (u16*)(ws + 16384 + 1048576);                 // 2 MiB
    u16*   Qpack  = (u16*)(ws + 16384 + 1048576 + 2097152);       // 512 KiB
    float* norms  = (float*)(ws + 3686400);                       // 3.5 MiB [u][key]
    u16*   rotKf  = (u16*)(ws + 8388608);                         // 256 MiB frag layout

    const size_t WS_NEED = 8388608ull + (size_t)MTOT * Hd * 2;

    hipMemsetAsync(best, 0, NU * BZn * sizeof(unsigned long long), stream);
    hipMemsetAsync(out, 0, sizeof(float), stream);

    k_qrot <<<64,  256, 0, stream>>>(query, R, Qrot);
    k_rpack<<<512, 256, 0, stream>>>(R, Rpack);
    k_qpack<<<128, 256, 0, stream>>>(Qrot, Qpack);

    if (ws_size >= WS_NEED) {
        hipMemsetAsync(norms, 0, (size_t)NU * MTOT * sizeof(float), stream);
        k_rot<<<8192, 256, 0, stream>>>(keys, Rpack, rotKf, norms);
        k_sim<<<MTOT / 64, 256, 0, stream>>>(rotKf, Qpack, norms, best);
    } else {
        hipFuncSetAttribute((const void*)k_main_fused,
                            hipFuncAttributeMaxDynamicSharedMemorySize, LDS_TOT_FB);
        k_main_fused<<<MTOT / 64, 1024, LDS_TOT_FB, stream>>>(keys, Rpack, Qpack, best);
    }
    k_final<<<NU * BZn, 256, 0, stream>>>(keys, R, Qrot, best, out);
}

// Round 11
// 1245.161 us; speedup vs baseline: 3.3671x; 1.2181x over previous
//
#include <hip/hip_runtime.h>
#include <hip/hip_bf16.h>
#include <stdint.h>

// ---------------- problem constants ----------------
static constexpr int Hd   = 1024;     // H_DIM
static constexpr int BZn  = 256;      // batch
static constexpr int MTOT = 131072;   // 32 * 4096 keys
static constexpr int NU   = 7;        // units

typedef float  f32x4  __attribute__((ext_vector_type(4)));
typedef short  bf16x8 __attribute__((ext_vector_type(8)));
typedef unsigned short u16;

__device__ __forceinline__ u16 f2bf(float f) {
    __hip_bfloat16 h = __float2bfloat16(f);   // RNE
    return *reinterpret_cast<u16*>(&h);
}

// ---------------- prep kernels ----------------

// Qrot[256][1024] = query @ R  (f32). 64 blocks x 256.
__global__ void k_qrot(const float* __restrict__ query, const float* __restrict__ R,
                       float* __restrict__ Qrot) {
    __shared__ float qt[4][Hd];
    const int t = threadIdx.x;
    const int r0 = blockIdx.x * 4;
    for (int r = 0; r < 4; ++r)
        *(float4*)(&qt[r][t * 4]) = *(const float4*)(query + (long long)(r0 + r) * Hd + t * 4);
    __syncthreads();
    float acc[4][4] = {};
    for (int k = 0; k < Hd; ++k) {
        float4 rv = *(const float4*)(R + (long long)k * Hd + t * 4);
#pragma unroll
        for (int r = 0; r < 4; ++r) {
            float qv = qt[r][k];
            acc[r][0] += qv * rv.x; acc[r][1] += qv * rv.y;
            acc[r][2] += qv * rv.z; acc[r][3] += qv * rv.w;
        }
    }
    for (int r = 0; r < 4; ++r) {
        float4 o; o.x = acc[r][0]; o.y = acc[r][1]; o.z = acc[r][2]; o.w = acc[r][3];
        *(float4*)(Qrot + (long long)(r0 + r) * Hd + t * 4) = o;
    }
}

// Rpack: B-fragment layout for mfma_f32_16x16x32_bf16.
// frag id = (c0/16)*32 + (k0/32); lane l holds B[k0+(l>>4)*8+j][c0+(l&15)], j=0..7.
__global__ void k_rpack(const float* __restrict__ R, u16* __restrict__ Rpack) {
    const int gt = blockIdx.x * 256 + threadIdx.x;
    const int frag = gt >> 6, lam = gt & 63;
    const int cblk = frag >> 5, kblk = frag & 31;
    const int c  = cblk * 16 + (lam & 15);
    const int k0 = kblk * 32 + (lam >> 4) * 8;
    union { bf16x8 v; u16 u[8]; } p;
#pragma unroll
    for (int j = 0; j < 8; ++j) p.u[j] = f2bf(R[(long long)(k0 + j) * Hd + c]);
    *(bf16x8*)(Rpack + (long long)frag * 512 + lam * 8) = p.v;
}

// Qpack: A-fragment layout. frag id = (c0/32)*16 + (q0/16);
// lane l holds A[q0+(l&15)][c0+(l>>4)*8+j].
__global__ void k_qpack(const float* __restrict__ Qrot, u16* __restrict__ Qpack) {
    const int gt = blockIdx.x * 256 + threadIdx.x;
    const int frag = gt >> 6, lam = gt & 63;
    const int cblk = frag >> 4, qblk = frag & 15;
    const int q  = qblk * 16 + (lam & 15);
    const int c0 = cblk * 32 + (lam >> 4) * 8;
    union { bf16x8 v; u16 u[8]; } p;
#pragma unroll
    for (int j = 0; j < 8; ++j) p.u[j] = f2bf(Qrot[(long long)q * Hd + c0 + j]);
    *(bf16x8*)(Qpack + (long long)frag * 512 + lam * 8) = p.v;
}

// ---------------- fused main: rotate 128keys x 256cols, then sims+argmax in-block ----
// grid: bx = tkey*4 + cg  (tkey 0..1023, cg = 256-col group 0..3)
// 512 thr = 8 waves. Rotation: wave (wq=w>>2: 64-key half, wc=w&3: 64-col quarter),
// acc[4][4] frags, BK=32 double-buffered LDS A-staging (k_rot-verified loop).
// Then: norms (f32) -> normP LDS; acc -> T LDS (k_rot-verified bounce layout);
// sims: wave (qh=w>>2: 128-q half, kq=w&3: 32-key quarter), B-frags from T,
// A-frags from Qpack; per-unit flush with packed-u32 argmax (k_sim-verified).
static constexpr int LDS_ABUF = 0;        // 2 x 10240
static constexpr int LDS_T    = 20480;    // 8 subtiles x 8704 (32 keys x 128 cols, stride 272)
static constexpr int LDS_NP   = 90112;    // 4 wc x 128 keys x f32 = 2048
static constexpr int LDS_TOT  = 92160;

__global__ __launch_bounds__(512, 2)
void k_fused(const float* __restrict__ keys, const u16* __restrict__ Rp,
             const u16* __restrict__ Qp, unsigned long long* __restrict__ best) {
    extern __shared__ char smem[];
    char*  abuf0 = smem + LDS_ABUF;
    char*  abuf1 = smem + LDS_ABUF + 10240;
    char*  T     = smem + LDS_T;
    float* normP = (float*)(smem + LDS_NP);

    const int t   = threadIdx.x;
    const int lam = t & 63;
    const int w   = t >> 6;
    const int l15 = lam & 15;
    const int lg  = lam >> 4;
    const int wq  = w >> 2;            // rotation: key half
    const int wc  = w & 3;             // rotation: col quarter

    const int bx   = blockIdx.x;
    const int tkey = bx >> 2;
    const int cg   = bx & 3;           // 256-col group
    const int kb   = tkey * 128;

    // ---- A staging geometry: thread t stages row sr = t>>2, 8 floats at (t&3)*8 ----
    const int sr = t >> 2, sc = t & 3;
    const float* apt = keys + (long long)(kb + sr) * Hd + sc * 8;
    const int sdst = sr * 80 + sc * 16;

    // ---- B-frag stream base: cblk = cg*16 + wc*4 + n; fid = cblk*32 + s ----
    const char* bB = (const char*)Rp + (long long)((cg * 16 + wc * 4) * 32) * 1024 + lam * 16;

    f32x4 acc[4][4];
#pragma unroll
    for (int m = 0; m < 4; ++m)
#pragma unroll
        for (int n = 0; n < 4; ++n) acc[m][n] = (f32x4){0.f, 0.f, 0.f, 0.f};

    // prologue prefetch (stage 0)
    float4 ar0 = *(const float4*)(apt);
    float4 ar1 = *(const float4*)(apt + 4);
    bf16x8 nb[4];
#pragma unroll
    for (int n = 0; n < 4; ++n) nb[n] = *(const bf16x8*)(bB + (long long)(n * 32) * 1024);

#pragma unroll 2
    for (int s = 0; s < 32; ++s) {
        char* buf = (s & 1) ? abuf1 : abuf0;
        // convert + write staged A (one b128 per thread)
        union { bf16x8 v; u16 u[8]; } p;
        p.u[0] = f2bf(ar0.x); p.u[1] = f2bf(ar0.y); p.u[2] = f2bf(ar0.z); p.u[3] = f2bf(ar0.w);
        p.u[4] = f2bf(ar1.x); p.u[5] = f2bf(ar1.y); p.u[6] = f2bf(ar1.z); p.u[7] = f2bf(ar1.w);
        *(bf16x8*)(buf + sdst) = p.v;

        // prefetch next stage (clamped)
        const int sn = (s < 31) ? s + 1 : 31;
        ar0 = *(const float4*)(apt + sn * 32);
        ar1 = *(const float4*)(apt + sn * 32 + 4);
        bf16x8 cbv[4];
#pragma unroll
        for (int n = 0; n < 4; ++n) cbv[n] = nb[n];
#pragma unroll
        for (int n = 0; n < 4; ++n)
            nb[n] = *(const bf16x8*)(bB + (long long)(n * 32 + sn) * 1024);

        __syncthreads();   // staged A visible (also fences prev stage's reads)

#pragma unroll
        for (int m = 0; m < 4; ++m) {
            int row = wq * 64 + m * 16 + l15;
            bf16x8 a = *(const bf16x8*)(buf + row * 80 + lg * 16);
#pragma unroll
            for (int n = 0; n < 4; ++n)
                acc[m][n] = __builtin_amdgcn_mfma_f32_16x16x32_bf16(a, cbv[n], acc[m][n], 0, 0, 0);
        }
    }
    __syncthreads();   // all rotation MFMAs done; abuf/T region repurpose safe

    // ---- norms (f32, per key over this wave's 64 cols) -> normP[wc][key] ----
#pragma unroll
    for (int m = 0; m < 4; ++m) {
#pragma unroll
        for (int e = 0; e < 4; ++e) {
            float s = 0.f;
#pragma unroll
            for (int n = 0; n < 4; ++n) { float v = acc[m][n][e]; s = fmaf(v, v, s); }
            s += __shfl_xor(s, 1); s += __shfl_xor(s, 2);
            s += __shfl_xor(s, 4); s += __shfl_xor(s, 8);
            if (l15 == 0) normP[wc * 128 + wq * 64 + m * 16 + lg * 4 + e] = s;
        }
    }

    // ---- bounce acc -> T subtiles (32 keys x 128 cols, stride 272) ----
    // subtile id = kt*2 + ct; kt = key/32 (0..3), ct = col/128 (0..1)
#pragma unroll
    for (int m = 0; m < 4; ++m) {
        char* Ts = T + ((wq * 2 + (m >> 1)) * 2 + (wc >> 1)) * 8704;
#pragma unroll
        for (int n = 0; n < 4; ++n) {
            int tcol = (wc & 1) * 64 + n * 16 + l15;
#pragma unroll
            for (int e = 0; e < 4; ++e) {
                int trow = (m & 1) * 16 + lg * 4 + e;
                *(u16*)(Ts + trow * 272 + tcol * 2) = f2bf(acc[m][n][e]);
            }
        }
    }
    __syncthreads();   // T + normP visible

    // ==== sims phase: wave = (qh = w>>2: 128 queries, kq = w&3: 32 keys) ====
    const int qh = w >> 2;
    const int kq = w & 3;
    const int fmask8 = (cg < 2) ? 0x80 : (cg == 2) ? 0x88 : 0xA8;

    f32x4 acc2[8][2];
#pragma unroll
    for (int mf = 0; mf < 8; ++mf) { acc2[mf][0] = (f32x4){0,0,0,0}; acc2[mf][1] = (f32x4){0,0,0,0}; }

    int u    = (cg < 2) ? cg : (cg == 2) ? 2 : 4;
    int prev = 0;

#pragma unroll
    for (int st = 0; st < 8; ++st) {
        // A-frags (Qpack, L2-hot): fid = (cg*8+st)*16 + qh*8 + mf
        bf16x8 aq[8];
#pragma unroll
        for (int mf = 0; mf < 8; ++mf)
            aq[mf] = *(const bf16x8*)((const char*)Qp +
                        (long long)((cg * 8 + st) * 16 + qh * 8 + mf) * 1024 + lam * 16);
        // B-frags from T: key = kq*32 + nf*16 + l15, cols st*32 + lg*8 + j
        bf16x8 bk[2];
        {
            const char* Ts = T + (kq * 2 + (st >> 2)) * 8704;
#pragma unroll
            for (int nf = 0; nf < 2; ++nf)
                bk[nf] = *(const bf16x8*)(Ts + (nf * 16 + l15) * 272 + (st & 3) * 64 + lg * 16);
        }
#pragma unroll
        for (int mf = 0; mf < 8; ++mf) {
            acc2[mf][0] = __builtin_amdgcn_mfma_f32_16x16x32_bf16(aq[mf], bk[0], acc2[mf][0], 0, 0, 0);
            acc2[mf][1] = __builtin_amdgcn_mfma_f32_16x16x32_bf16(aq[mf], bk[1], acc2[mf][1], 0, 0, 0);
        }

        if ((fmask8 >> st) & 1) {
            // ---- flush unit u: cols [prev..st]*32, wc quarters prev>>1 .. st>>1 ----
            const int wc0 = prev >> 1, wc1 = st >> 1;
            float rn[2];
#pragma unroll
            for (int nf = 0; nf < 2; ++nf) {
                int key = kq * 32 + nf * 16 + l15;
                float nv = 0.f;
                for (int q2 = wc0; q2 <= wc1; ++q2) nv += normP[q2 * 128 + key];
                rn[nf] = 1.0f / fmaxf(sqrtf(nv), 1e-3f);
            }
#pragma unroll
            for (int mf = 0; mf < 8; ++mf) {
#pragma unroll
                for (int e = 0; e < 4; ++e) {
                    float v0 = acc2[mf][0][e] * rn[0];
                    float v1 = acc2[mf][1][e] * rn[1];
                    float bv; int bi5;
                    if (v1 > v0) { bv = v1; bi5 = 16 + l15; }
                    else         { bv = v0; bi5 = l15; }
                    unsigned int ui = __float_as_uint(bv);
                    unsigned int mp = ui ^ (((int)ui < 0) ? 0xFFFFFFFFu : 0x80000000u);
                    unsigned int enc = (mp & 0xFFFFFFC0u) | (63u - (unsigned int)bi5);
#pragma unroll
                    for (int mask = 1; mask <= 8; mask <<= 1) {
                        unsigned int o = __shfl_xor(enc, mask);
                        enc = (o > enc) ? o : enc;
                    }
                    if (l15 == 0) {
                        unsigned int gl = (unsigned int)(kb + kq * 32 + (63 - (int)(enc & 63u)));
                        unsigned long long e64 =
                            ((unsigned long long)(enc & 0xFFFFFFC0u) << 32) |
                            (unsigned long long)(0xFFFFFFFFu - gl);
                        int qq = qh * 128 + mf * 16 + lg * 4 + e;
                        unsigned long long* addr = best + u * BZn + qq;
                        if (e64 > *addr) atomicMax(addr, e64);
                    }
                    acc2[mf][0][e] = 0.f;
                    acc2[mf][1][e] = 0.f;
                }
            }
            ++u;
            prev = st + 1;
        }
    }
}

// ---------------- finish: exact f32 cosine of the winners ----------------
__global__ void k_final(const float* __restrict__ keys, const float* __restrict__ R,
                        const float* __restrict__ Qrot,
                        const unsigned long long* __restrict__ best, float* __restrict__ out) {
    const int fid = blockIdx.x;
    const int u = fid >> 8, b = fid & 255;
    int off, d;
    if (u < 2)      { off = u * 256;            d = 256; }
    else if (u < 5) { off = 512 + (u - 2) * 128; d = 128; }
    else            { off = 896 + (u - 5) * 64;  d = 64;  }

    unsigned long long ent = best[fid];
    if (ent == 0ull) return;

    __shared__ float krow[Hd];
    __shared__ float red[12];
    const int t = threadIdx.x;
    unsigned int gl = 0xFFFFFFFFu - (unsigned int)(ent & 0xFFFFFFFFull);
    const float* kp = keys + (long long)gl * Hd;
    *(float4*)(&krow[t * 4]) = *(const float4*)(kp + t * 4);
    __syncthreads();

    float pn = 0.f, pq = 0.f, pk = 0.f;
    if (t < d) {
        float kr = 0.f;
        for (int k = 0; k < Hd; ++k) kr += krow[k] * R[(long long)k * Hd + off + t];
        float qv = Qrot[(long long)b * Hd + off + t];
        pn = qv * kr; pq = qv * qv; pk = kr * kr;
    }
    for (int mask = 1; mask <= 32; mask <<= 1) {
        pn += __shfl_xor(pn, mask); pq += __shfl_xor(pq, mask); pk += __shfl_xor(pk, mask);
    }
    if ((t & 63) == 0) { red[t >> 6] = pn; red[4 + (t >> 6)] = pq; red[8 + (t >> 6)] = pk; }
    __syncthreads();
    if (t == 0) {
        float nm = red[0] + red[1] + red[2] + red[3];
        float qq = red[4] + red[5] + red[6] + red[7];
        float kk = red[8] + red[9] + red[10] + red[11];
        float cosv = nm / (fmaxf(sqrtf(qq), 1e-8f) * fmaxf(sqrtf(kk), 1e-8f));
        atomicAdd(out, -cosv * (float)d / (256.0f * 1024.0f));
    }
}

// ---------------- launch ----------------
extern "C" void kernel_launch(void* const* d_in, const int* in_sizes, int n_in,
                              void* d_out, int out_size, void* d_ws, size_t ws_size,
                              hipStream_t stream) {
    (void)in_sizes; (void)n_in; (void)out_size; (void)ws_size;
    const float* query = (const float*)d_in[0];
    const float* keys  = (const float*)d_in[1];
    const float* R     = (const float*)d_in[2];
    float* out = (float*)d_out;
    char* ws = (char*)d_ws;

    unsigned long long* best = (unsigned long long*)ws;           // 16 KiB slot
    float* Qrot   = (float*)(ws + 16384);                         // 1 MiB
    u16*   Rpack  = (u16*)(ws + 16384 + 1048576);                 // 2 MiB
    u16*   Qpack  = (u16*)(ws + 16384 + 1048576 + 2097152);       // 512 KiB
    // total ws use: ~3.6 MiB

    hipMemsetAsync(best, 0, NU * BZn * sizeof(unsigned long long), stream);
    hipMemsetAsync(out, 0, sizeof(float), stream);

    k_qrot <<<64,  256, 0, stream>>>(query, R, Qrot);
    k_rpack<<<512, 256, 0, stream>>>(R, Rpack);
    k_qpack<<<128, 256, 0, stream>>>(Qrot, Qpack);

    hipFuncSetAttribute((const void*)k_fused,
                        hipFuncAttributeMaxDynamicSharedMemorySize, LDS_TOT);
    k_fused<<<(MTOT / 128) * 4, 512, LDS_TOT, stream>>>(keys, Rpack, Qpack, best);

    k_final<<<NU * BZn, 256, 0, stream>>>(keys, R, Qrot, best, out);
}

// Round 12
// 1230.864 us; speedup vs baseline: 3.4062x; 1.0116x over previous
//
#include <hip/hip_runtime.h>
#include <hip/hip_bf16.h>
#include <stdint.h>

// ---------------- problem constants ----------------
static constexpr int Hd   = 1024;     // H_DIM
static constexpr int BZn  = 256;      // batch
static constexpr int MTOT = 131072;   // 32 * 4096 keys
static constexpr int NU   = 7;        // units

typedef float  f32x4  __attribute__((ext_vector_type(4)));
typedef short  bf16x8 __attribute__((ext_vector_type(8)));
typedef unsigned short u16;

__device__ __forceinline__ u16 f2bf(float f) {
    __hip_bfloat16 h = __float2bfloat16(f);   // RNE
    return *reinterpret_cast<u16*>(&h);
}

// Counted-wait barrier (T3/T4 minimum form): waits LDS ops only; vmem loads
// stay in flight across the barrier (no vmcnt(0) drain -> latency hides
// under the MFMA phase). LDS-safe: lgkmcnt(0) covers all ds reads+writes.
__device__ __forceinline__ void block_sync_lds() {
    asm volatile("s_waitcnt lgkmcnt(0)" ::: "memory");
    __builtin_amdgcn_s_barrier();
}

// ---------------- prep kernels ----------------

// Qrot[256][1024] = query @ R  (f32). 64 blocks x 256.
__global__ void k_qrot(const float* __restrict__ query, const float* __restrict__ R,
                       float* __restrict__ Qrot) {
    __shared__ float qt[4][Hd];
    const int t = threadIdx.x;
    const int r0 = blockIdx.x * 4;
    for (int r = 0; r < 4; ++r)
        *(float4*)(&qt[r][t * 4]) = *(const float4*)(query + (long long)(r0 + r) * Hd + t * 4);
    __syncthreads();
    float acc[4][4] = {};
    for (int k = 0; k < Hd; ++k) {
        float4 rv = *(const float4*)(R + (long long)k * Hd + t * 4);
#pragma unroll
        for (int r = 0; r < 4; ++r) {
            float qv = qt[r][k];
            acc[r][0] += qv * rv.x; acc[r][1] += qv * rv.y;
            acc[r][2] += qv * rv.z; acc[r][3] += qv * rv.w;
        }
    }
    for (int r = 0; r < 4; ++r) {
        float4 o; o.x = acc[r][0]; o.y = acc[r][1]; o.z = acc[r][2]; o.w = acc[r][3];
        *(float4*)(Qrot + (long long)(r0 + r) * Hd + t * 4) = o;
    }
}

// Rpack: B-fragment layout for mfma_f32_16x16x32_bf16.
// frag id = (c0/16)*32 + (k0/32); lane l holds B[k0+(l>>4)*8+j][c0+(l&15)], j=0..7.
__global__ void k_rpack(const float* __restrict__ R, u16* __restrict__ Rpack) {
    const int gt = blockIdx.x * 256 + threadIdx.x;
    const int frag = gt >> 6, lam = gt & 63;
    const int cblk = frag >> 5, kblk = frag & 31;
    const int c  = cblk * 16 + (lam & 15);
    const int k0 = kblk * 32 + (lam >> 4) * 8;
    union { bf16x8 v; u16 u[8]; } p;
#pragma unroll
    for (int j = 0; j < 8; ++j) p.u[j] = f2bf(R[(long long)(k0 + j) * Hd + c]);
    *(bf16x8*)(Rpack + (long long)frag * 512 + lam * 8) = p.v;
}

// Qpack: A-fragment layout. frag id = (c0/32)*16 + (q0/16);
// lane l holds A[q0+(l&15)][c0+(l>>4)*8+j].
__global__ void k_qpack(const float* __restrict__ Qrot, u16* __restrict__ Qpack) {
    const int gt = blockIdx.x * 256 + threadIdx.x;
    const int frag = gt >> 6, lam = gt & 63;
    const int cblk = frag >> 4, qblk = frag & 15;
    const int q  = qblk * 16 + (lam & 15);
    const int c0 = cblk * 32 + (lam >> 4) * 8;
    union { bf16x8 v; u16 u[8]; } p;
#pragma unroll
    for (int j = 0; j < 8; ++j) p.u[j] = f2bf(Qrot[(long long)q * Hd + c0 + j]);
    *(bf16x8*)(Qpack + (long long)frag * 512 + lam * 8) = p.v;
}

// ---------------- fused main: rotate 128keys x 256cols, then sims+argmax in-block ----
// logical id: bid = tkey*4 + cg; XCD-swizzled so the 4 cg-blocks of one tkey
// are consecutive within an XCD chunk (keys L2/L3 reuse). 4096 % 8 == 0.
static constexpr int LDS_ABUF = 0;        // 2 x 10240
static constexpr int LDS_T    = 20480;    // 8 subtiles x 8704 (32 keys x 128 cols, stride 272)
static constexpr int LDS_NP   = 90112;    // 4 wc x 128 keys x f32 = 2048
static constexpr int LDS_TOT  = 92160;

__global__ __launch_bounds__(512, 2)
void k_fused(const float* __restrict__ keys, const u16* __restrict__ Rp,
             const u16* __restrict__ Qp, unsigned long long* __restrict__ best) {
    extern __shared__ char smem[];
    char*  abuf0 = smem + LDS_ABUF;
    char*  abuf1 = smem + LDS_ABUF + 10240;
    char*  T     = smem + LDS_T;
    float* normP = (float*)(smem + LDS_NP);

    const int t   = threadIdx.x;
    const int lam = t & 63;
    const int w   = t >> 6;
    const int l15 = lam & 15;
    const int lg  = lam >> 4;
    const int wq  = w >> 2;            // rotation: key half
    const int wc  = w & 3;             // rotation: col quarter

    // T1: bijective XCD swizzle (8 XCDs, 4096 blocks -> 512 per XCD chunk)
    const int bid  = (blockIdx.x & 7) * 512 + (blockIdx.x >> 3);
    const int tkey = bid >> 2;
    const int cg   = bid & 3;          // 256-col group
    const int kb   = tkey * 128;

    // ---- A staging geometry: thread t stages row sr = t>>2, 8 floats at (t&3)*8 ----
    const int sr = t >> 2, sc = t & 3;
    const float* apt = keys + (long long)(kb + sr) * Hd + sc * 8;
    const int sdst = sr * 80 + sc * 16;

    // ---- B-frag stream base: cblk = cg*16 + wc*4 + n; fid = cblk*32 + s ----
    const char* bB = (const char*)Rp + (long long)((cg * 16 + wc * 4) * 32) * 1024 + lam * 16;

    f32x4 acc[4][4];
#pragma unroll
    for (int m = 0; m < 4; ++m)
#pragma unroll
        for (int n = 0; n < 4; ++n) acc[m][n] = (f32x4){0.f, 0.f, 0.f, 0.f};

    // prologue prefetch (stage 0)
    float4 ar0 = *(const float4*)(apt);
    float4 ar1 = *(const float4*)(apt + 4);
    bf16x8 nb[4];
#pragma unroll
    for (int n = 0; n < 4; ++n) nb[n] = *(const bf16x8*)(bB + (long long)(n * 32) * 1024);

#pragma unroll 2
    for (int s = 0; s < 32; ++s) {
        char* buf = (s & 1) ? abuf1 : abuf0;
        // convert + write staged A (one b128 per thread) — compiler inserts
        // counted vmcnt for ar; the 4 nb loads stay outstanding.
        union { bf16x8 v; u16 u[8]; } p;
        p.u[0] = f2bf(ar0.x); p.u[1] = f2bf(ar0.y); p.u[2] = f2bf(ar0.z); p.u[3] = f2bf(ar0.w);
        p.u[4] = f2bf(ar1.x); p.u[5] = f2bf(ar1.y); p.u[6] = f2bf(ar1.z); p.u[7] = f2bf(ar1.w);
        *(bf16x8*)(buf + sdst) = p.v;

        // prefetch next stage (clamped); these loads FLY ACROSS the barrier
        const int sn = (s < 31) ? s + 1 : 31;
        ar0 = *(const float4*)(apt + sn * 32);
        ar1 = *(const float4*)(apt + sn * 32 + 4);
        bf16x8 cbv[4];
#pragma unroll
        for (int n = 0; n < 4; ++n) cbv[n] = nb[n];
#pragma unroll
        for (int n = 0; n < 4; ++n)
            nb[n] = *(const bf16x8*)(bB + (long long)(n * 32 + sn) * 1024);

        block_sync_lds();   // lgkmcnt(0) + raw barrier: NO vmcnt drain

#pragma unroll
        for (int m = 0; m < 4; ++m) {
            int row = wq * 64 + m * 16 + l15;
            bf16x8 a = *(const bf16x8*)(buf + row * 80 + lg * 16);
#pragma unroll
            for (int n = 0; n < 4; ++n)
                acc[m][n] = __builtin_amdgcn_mfma_f32_16x16x32_bf16(a, cbv[n], acc[m][n], 0, 0, 0);
        }
    }
    block_sync_lds();   // rotation reads done; T/normP writes follow

    // ---- norms (f32, per key over this wave's 64 cols) -> normP[wc][key] ----
#pragma unroll
    for (int m = 0; m < 4; ++m) {
#pragma unroll
        for (int e = 0; e < 4; ++e) {
            float s = 0.f;
#pragma unroll
            for (int n = 0; n < 4; ++n) { float v = acc[m][n][e]; s = fmaf(v, v, s); }
            s += __shfl_xor(s, 1); s += __shfl_xor(s, 2);
            s += __shfl_xor(s, 4); s += __shfl_xor(s, 8);
            if (l15 == 0) normP[wc * 128 + wq * 64 + m * 16 + lg * 4 + e] = s;
        }
    }

    // ---- bounce acc -> T subtiles (32 keys x 128 cols, stride 272) ----
    // subtile id = kt*2 + ct; kt = key/32 (0..3), ct = col/128 (0..1)
#pragma unroll
    for (int m = 0; m < 4; ++m) {
        char* Ts = T + ((wq * 2 + (m >> 1)) * 2 + (wc >> 1)) * 8704;
#pragma unroll
        for (int n = 0; n < 4; ++n) {
            int tcol = (wc & 1) * 64 + n * 16 + l15;
#pragma unroll
            for (int e = 0; e < 4; ++e) {
                int trow = (m & 1) * 16 + lg * 4 + e;
                *(u16*)(Ts + trow * 272 + tcol * 2) = f2bf(acc[m][n][e]);
            }
        }
    }
    block_sync_lds();   // T + normP visible

    // ==== sims phase: wave = (qh = w>>2: 128 queries, kq = w&3: 32 keys) ====
    const int qh = w >> 2;
    const int kq = w & 3;
    const int fmask8 = (cg < 2) ? 0x80 : (cg == 2) ? 0x88 : 0xA8;

    f32x4 acc2[8][2];
#pragma unroll
    for (int mf = 0; mf < 8; ++mf) { acc2[mf][0] = (f32x4){0,0,0,0}; acc2[mf][1] = (f32x4){0,0,0,0}; }

    int u    = (cg < 2) ? cg : (cg == 2) ? 2 : 4;
    int prev = 0;

#pragma unroll
    for (int st = 0; st < 8; ++st) {
        // A-frags (Qpack, L2-hot): fid = (cg*8+st)*16 + qh*8 + mf
        bf16x8 aq[8];
#pragma unroll
        for (int mf = 0; mf < 8; ++mf)
            aq[mf] = *(const bf16x8*)((const char*)Qp +
                        (long long)((cg * 8 + st) * 16 + qh * 8 + mf) * 1024 + lam * 16);
        // B-frags from T: key = kq*32 + nf*16 + l15, cols st*32 + lg*8 + j
        bf16x8 bk[2];
        {
            const char* Ts = T + (kq * 2 + (st >> 2)) * 8704;
#pragma unroll
            for (int nf = 0; nf < 2; ++nf)
                bk[nf] = *(const bf16x8*)(Ts + (nf * 16 + l15) * 272 + (st & 3) * 64 + lg * 16);
        }
#pragma unroll
        for (int mf = 0; mf < 8; ++mf) {
            acc2[mf][0] = __builtin_amdgcn_mfma_f32_16x16x32_bf16(aq[mf], bk[0], acc2[mf][0], 0, 0, 0);
            acc2[mf][1] = __builtin_amdgcn_mfma_f32_16x16x32_bf16(aq[mf], bk[1], acc2[mf][1], 0, 0, 0);
        }

        if ((fmask8 >> st) & 1) {
            // ---- flush unit u: cols [prev..st]*32, wc quarters prev>>1 .. st>>1 ----
            const int wc0 = prev >> 1, wc1 = st >> 1;
            float rn[2];
#pragma unroll
            for (int nf = 0; nf < 2; ++nf) {
                int key = kq * 32 + nf * 16 + l15;
                float nv = 0.f;
                for (int q2 = wc0; q2 <= wc1; ++q2) nv += normP[q2 * 128 + key];
                rn[nf] = 1.0f / fmaxf(sqrtf(nv), 1e-3f);
            }
#pragma unroll
            for (int mf = 0; mf < 8; ++mf) {
#pragma unroll
                for (int e = 0; e < 4; ++e) {
                    float v0 = acc2[mf][0][e] * rn[0];
                    float v1 = acc2[mf][1][e] * rn[1];
                    float bv; int bi5;
                    if (v1 > v0) { bv = v1; bi5 = 16 + l15; }
                    else         { bv = v0; bi5 = l15; }
                    unsigned int ui = __float_as_uint(bv);
                    unsigned int mp = ui ^ (((int)ui < 0) ? 0xFFFFFFFFu : 0x80000000u);
                    unsigned int enc = (mp & 0xFFFFFFC0u) | (63u - (unsigned int)bi5);
#pragma unroll
                    for (int mask = 1; mask <= 8; mask <<= 1) {
                        unsigned int o = __shfl_xor(enc, mask);
                        enc = (o > enc) ? o : enc;
                    }
                    if (l15 == 0) {
                        unsigned int gl = (unsigned int)(kb + kq * 32 + (63 - (int)(enc & 63u)));
                        unsigned long long e64 =
                            ((unsigned long long)(enc & 0xFFFFFFC0u) << 32) |
                            (unsigned long long)(0xFFFFFFFFu - gl);
                        int qq = qh * 128 + mf * 16 + lg * 4 + e;
                        unsigned long long* addr = best + u * BZn + qq;
                        if (e64 > *addr) atomicMax(addr, e64);
                    }
                    acc2[mf][0][e] = 0.f;
                    acc2[mf][1][e] = 0.f;
                }
            }
            ++u;
            prev = st + 1;
        }
    }
}

// ---------------- finish: exact f32 cosine of the winners ----------------
__global__ void k_final(const float* __restrict__ keys, const float* __restrict__ R,
                        const float* __restrict__ Qrot,
                        const unsigned long long* __restrict__ best, float* __restrict__ out) {
    const int fid = blockIdx.x;
    const int u = fid >> 8, b = fid & 255;
    int off, d;
    if (u < 2)      { off = u * 256;            d = 256; }
    else if (u < 5) { off = 512 + (u - 2) * 128; d = 128; }
    else            { off = 896 + (u - 5) * 64;  d = 64;  }

    unsigned long long ent = best[fid];
    if (ent == 0ull) return;

    __shared__ float krow[Hd];
    __shared__ float red[12];
    const int t = threadIdx.x;
    unsigned int gl = 0xFFFFFFFFu - (unsigned int)(ent & 0xFFFFFFFFull);
    const float* kp = keys + (long long)gl * Hd;
    *(float4*)(&krow[t * 4]) = *(const float4*)(kp + t * 4);
    __syncthreads();

    float pn = 0.f, pq = 0.f, pk = 0.f;
    if (t < d) {
        float kr = 0.f;
        for (int k = 0; k < Hd; ++k) kr += krow[k] * R[(long long)k * Hd + off + t];
        float qv = Qrot[(long long)b * Hd + off + t];
        pn = qv * kr; pq = qv * qv; pk = kr * kr;
    }
    for (int mask = 1; mask <= 32; mask <<= 1) {
        pn += __shfl_xor(pn, mask); pq += __shfl_xor(pq, mask); pk += __shfl_xor(pk, mask);
    }
    if ((t & 63) == 0) { red[t >> 6] = pn; red[4 + (t >> 6)] = pq; red[8 + (t >> 6)] = pk; }
    __syncthreads();
    if (t == 0) {
        float nm = red[0] + red[1] + red[2] + red[3];
        float qq = red[4] + red[5] + red[6] + red[7];
        float kk = red[8] + red[9] + red[10] + red[11];
        float cosv = nm / (fmaxf(sqrtf(qq), 1e-8f) * fmaxf(sqrtf(kk), 1e-8f));
        atomicAdd(out, -cosv * (float)d / (256.0f * 1024.0f));
    }
}

// ---------------- launch ----------------
extern "C" void kernel_launch(void* const* d_in, const int* in_sizes, int n_in,
                              void* d_out, int out_size, void* d_ws, size_t ws_size,
                              hipStream_t stream) {
    (void)in_sizes; (void)n_in; (void)out_size; (void)ws_size;
    const float* query = (const float*)d_in[0];
    const float* keys  = (const float*)d_in[1];
    const float* R     = (const float*)d_in[2];
    float* out = (float*)d_out;
    char* ws = (char*)d_ws;

    unsigned long long* best = (unsigned long long*)ws;           // 16 KiB slot
    float* Qrot   = (float*)(ws + 16384);                         // 1 MiB
    u16*   Rpack  = (u16*)(ws + 16384 + 1048576);                 // 2 MiB
    u16*   Qpack  = (u16*)(ws + 16384 + 1048576 + 2097152);       // 512 KiB

    hipMemsetAsync(best, 0, NU * BZn * sizeof(unsigned long long), stream);
    hipMemsetAsync(out, 0, sizeof(float), stream);

    k_qrot <<<64,  256, 0, stream>>>(query, R, Qrot);
    k_rpack<<<512, 256, 0, stream>>>(R, Rpack);
    k_qpack<<<128, 256, 0, stream>>>(Qrot, Qpack);

    hipFuncSetAttribute((const void*)k_fused,
                        hipFuncAttributeMaxDynamicSharedMemorySize, LDS_TOT);
    k_fused<<<(MTOT / 128) * 4, 512, LDS_TOT, stream>>>(keys, Rpack, Qpack, best);

    k_final<<<NU * BZn, 256, 0, stream>>>(keys, R, Qrot, best, out);
}

// Round 13
// 922.762 us; speedup vs baseline: 4.5436x; 1.3339x over previous
//
#include <hip/hip_runtime.h>
#include <hip/hip_bf16.h>
#include <stdint.h>

// ---------------- problem constants ----------------
static constexpr int Hd   = 1024;     // H_DIM
static constexpr int BZn  = 256;      // batch
static constexpr int MTOT = 131072;   // 32 * 4096 keys
static constexpr int NU   = 7;        // units

typedef float  f32x4  __attribute__((ext_vector_type(4)));
typedef short  bf16x8 __attribute__((ext_vector_type(8)));
typedef unsigned short u16;

__device__ __forceinline__ u16 f2bf(float f) {
    __hip_bfloat16 h = __float2bfloat16(f);   // RNE
    return *reinterpret_cast<u16*>(&h);
}

// Counted-wait barrier: waits LDS ops only; vmem loads stay in flight.
__device__ __forceinline__ void block_sync_lds() {
    asm volatile("s_waitcnt lgkmcnt(0)" ::: "memory");
    __builtin_amdgcn_s_barrier();
}

// ---------------- prep kernels ----------------

// Qrot[256][1024] = query @ R  (f32). 64 blocks x 256.
__global__ void k_qrot(const float* __restrict__ query, const float* __restrict__ R,
                       float* __restrict__ Qrot) {
    __shared__ float qt[4][Hd];
    const int t = threadIdx.x;
    const int r0 = blockIdx.x * 4;
    for (int r = 0; r < 4; ++r)
        *(float4*)(&qt[r][t * 4]) = *(const float4*)(query + (long long)(r0 + r) * Hd + t * 4);
    __syncthreads();
    float acc[4][4] = {};
    for (int k = 0; k < Hd; ++k) {
        float4 rv = *(const float4*)(R + (long long)k * Hd + t * 4);
#pragma unroll
        for (int r = 0; r < 4; ++r) {
            float qv = qt[r][k];
            acc[r][0] += qv * rv.x; acc[r][1] += qv * rv.y;
            acc[r][2] += qv * rv.z; acc[r][3] += qv * rv.w;
        }
    }
    for (int r = 0; r < 4; ++r) {
        float4 o; o.x = acc[r][0]; o.y = acc[r][1]; o.z = acc[r][2]; o.w = acc[r][3];
        *(float4*)(Qrot + (long long)(r0 + r) * Hd + t * 4) = o;
    }
}

// Rpack: B-fragment layout for mfma_f32_16x16x32_bf16.
// frag id = (c0/16)*32 + (k0/32); lane l holds B[k0+(l>>4)*8+j][c0+(l&15)], j=0..7.
__global__ void k_rpack(const float* __restrict__ R, u16* __restrict__ Rpack) {
    const int gt = blockIdx.x * 256 + threadIdx.x;
    const int frag = gt >> 6, lam = gt & 63;
    const int cblk = frag >> 5, kblk = frag & 31;
    const int c  = cblk * 16 + (lam & 15);
    const int k0 = kblk * 32 + (lam >> 4) * 8;
    union { bf16x8 v; u16 u[8]; } p;
#pragma unroll
    for (int j = 0; j < 8; ++j) p.u[j] = f2bf(R[(long long)(k0 + j) * Hd + c]);
    *(bf16x8*)(Rpack + (long long)frag * 512 + lam * 8) = p.v;
}

// Qpack: A-fragment layout. frag id = (c0/32)*16 + (q0/16);
// lane l holds A[q0+(l&15)][c0+(l>>4)*8+j].
__global__ void k_qpack(const float* __restrict__ Qrot, u16* __restrict__ Qpack) {
    const int gt = blockIdx.x * 256 + threadIdx.x;
    const int frag = gt >> 6, lam = gt & 63;
    const int cblk = frag >> 4, qblk = frag & 15;
    const int q  = qblk * 16 + (lam & 15);
    const int c0 = cblk * 32 + (lam >> 4) * 8;
    union { bf16x8 v; u16 u[8]; } p;
#pragma unroll
    for (int j = 0; j < 8; ++j) p.u[j] = f2bf(Qrot[(long long)q * Hd + c0 + j]);
    *(bf16x8*)(Qpack + (long long)frag * 512 + lam * 8) = p.v;
}

// ---------------- fused main: rotate 128keys x 256cols, then sims+argmax in-block ----
// LDS UNION (2 blocks/CU): abuf [0..20480) used only during rotation;
// T [0..69632) + normP [69632..71680) used only after rotation (barrier-separated).
static constexpr int LDS_ABUF0 = 0;
static constexpr int LDS_ABUF1 = 10240;
static constexpr int LDS_T     = 0;        // overlaps abuf (safe: phase-separated)
static constexpr int LDS_NP    = 69632;    // 4 wc x 128 keys x f32 = 2048
static constexpr int LDS_TOT   = 73728;    // <= 80 KiB -> 2 blocks/CU

__global__ __launch_bounds__(512, 4)
void k_fused(const float* __restrict__ keys, const u16* __restrict__ Rp,
             const u16* __restrict__ Qp, unsigned long long* __restrict__ best) {
    extern __shared__ char smem[];
    char*  abuf0 = smem + LDS_ABUF0;
    char*  abuf1 = smem + LDS_ABUF1;
    char*  T     = smem + LDS_T;
    float* normP = (float*)(smem + LDS_NP);

    const int t   = threadIdx.x;
    const int lam = t & 63;
    const int w   = t >> 6;
    const int l15 = lam & 15;
    const int lg  = lam >> 4;
    const int wq  = w >> 2;            // rotation: key half
    const int wc  = w & 3;             // rotation: col quarter

    // T1: bijective XCD swizzle (8 XCDs, 4096 blocks -> 512 per XCD chunk)
    const int bid  = (blockIdx.x & 7) * 512 + (blockIdx.x >> 3);
    const int tkey = bid >> 2;
    const int cg   = bid & 3;          // 256-col group
    const int kb   = tkey * 128;

    // ---- A staging geometry: thread t stages row sr = t>>2, 8 floats at (t&3)*8 ----
    const int sr = t >> 2, sc = t & 3;
    const float* apt = keys + (long long)(kb + sr) * Hd + sc * 8;
    const int sdst = sr * 80 + sc * 16;

    // ---- B-frag stream base: cblk = cg*16 + wc*4 + n; fid = cblk*32 + s ----
    const char* bB = (const char*)Rp + (long long)((cg * 16 + wc * 4) * 32) * 1024 + lam * 16;

    f32x4 acc[4][4];
#pragma unroll
    for (int m = 0; m < 4; ++m)
#pragma unroll
        for (int n = 0; n < 4; ++n) acc[m][n] = (f32x4){0.f, 0.f, 0.f, 0.f};

    // prologue prefetch (stage 0)
    float4 ar0 = *(const float4*)(apt);
    float4 ar1 = *(const float4*)(apt + 4);
    bf16x8 nb[4];
#pragma unroll
    for (int n = 0; n < 4; ++n) nb[n] = *(const bf16x8*)(bB + (long long)(n * 32) * 1024);

#pragma unroll 2
    for (int s = 0; s < 32; ++s) {
        char* buf = (s & 1) ? abuf1 : abuf0;
        // convert + write staged A (one b128 per thread)
        union { bf16x8 v; u16 u[8]; } p;
        p.u[0] = f2bf(ar0.x); p.u[1] = f2bf(ar0.y); p.u[2] = f2bf(ar0.z); p.u[3] = f2bf(ar0.w);
        p.u[4] = f2bf(ar1.x); p.u[5] = f2bf(ar1.y); p.u[6] = f2bf(ar1.z); p.u[7] = f2bf(ar1.w);
        *(bf16x8*)(buf + sdst) = p.v;

        // prefetch next stage (clamped); loads stay in flight across the barrier
        const int sn = (s < 31) ? s + 1 : 31;
        ar0 = *(const float4*)(apt + sn * 32);
        ar1 = *(const float4*)(apt + sn * 32 + 4);
        bf16x8 cbv[4];
#pragma unroll
        for (int n = 0; n < 4; ++n) cbv[n] = nb[n];
#pragma unroll
        for (int n = 0; n < 4; ++n)
            nb[n] = *(const bf16x8*)(bB + (long long)(n * 32 + sn) * 1024);

        block_sync_lds();   // lgkmcnt(0) + raw barrier: NO vmcnt drain

#pragma unroll
        for (int m = 0; m < 4; ++m) {
            int row = wq * 64 + m * 16 + l15;
            bf16x8 a = *(const bf16x8*)(buf + row * 80 + lg * 16);
#pragma unroll
            for (int n = 0; n < 4; ++n)
                acc[m][n] = __builtin_amdgcn_mfma_f32_16x16x32_bf16(a, cbv[n], acc[m][n], 0, 0, 0);
        }
    }
    block_sync_lds();   // rotation abuf reads done; T may overwrite abuf region

    // ---- norms (f32, per key over this wave's 64 cols) -> normP[wc][key] ----
#pragma unroll
    for (int m = 0; m < 4; ++m) {
#pragma unroll
        for (int e = 0; e < 4; ++e) {
            float s = 0.f;
#pragma unroll
            for (int n = 0; n < 4; ++n) { float v = acc[m][n][e]; s = fmaf(v, v, s); }
            s += __shfl_xor(s, 1); s += __shfl_xor(s, 2);
            s += __shfl_xor(s, 4); s += __shfl_xor(s, 8);
            if (l15 == 0) normP[wc * 128 + wq * 64 + m * 16 + lg * 4 + e] = s;
        }
    }

    // ---- bounce acc -> T subtiles (32 keys x 128 cols, stride 272) ----
    // subtile id = kt*2 + ct; kt = key/32 (0..3), ct = col/128 (0..1)
#pragma unroll
    for (int m = 0; m < 4; ++m) {
        char* Ts = T + ((wq * 2 + (m >> 1)) * 2 + (wc >> 1)) * 8704;
#pragma unroll
        for (int n = 0; n < 4; ++n) {
            int tcol = (wc & 1) * 64 + n * 16 + l15;
#pragma unroll
            for (int e = 0; e < 4; ++e) {
                int trow = (m & 1) * 16 + lg * 4 + e;
                *(u16*)(Ts + trow * 272 + tcol * 2) = f2bf(acc[m][n][e]);
            }
        }
    }
    block_sync_lds();   // T + normP visible

    // ==== sims phase: wave = (qh = w>>2: 128 queries, kq = w&3: 32 keys) ====
    const int qh = w >> 2;
    const int kq = w & 3;
    const int fmask8 = (cg < 2) ? 0x80 : (cg == 2) ? 0x88 : 0xA8;

    f32x4 acc2[8][2];
#pragma unroll
    for (int mf = 0; mf < 8; ++mf) { acc2[mf][0] = (f32x4){0,0,0,0}; acc2[mf][1] = (f32x4){0,0,0,0}; }

    int u    = (cg < 2) ? cg : (cg == 2) ? 2 : 4;
    int prev = 0;

#pragma unroll
    for (int st = 0; st < 8; ++st) {
        // A-frags (Qpack, L2-hot): fid = (cg*8+st)*16 + qh*8 + mf
        bf16x8 aq[8];
#pragma unroll
        for (int mf = 0; mf < 8; ++mf)
            aq[mf] = *(const bf16x8*)((const char*)Qp +
                        (long long)((cg * 8 + st) * 16 + qh * 8 + mf) * 1024 + lam * 16);
        // B-frags from T: key = kq*32 + nf*16 + l15, cols st*32 + lg*8 + j
        bf16x8 bk[2];
        {
            const char* Ts = T + (kq * 2 + (st >> 2)) * 8704;
#pragma unroll
            for (int nf = 0; nf < 2; ++nf)
                bk[nf] = *(const bf16x8*)(Ts + (nf * 16 + l15) * 272 + (st & 3) * 64 + lg * 16);
        }
#pragma unroll
        for (int mf = 0; mf < 8; ++mf) {
            acc2[mf][0] = __builtin_amdgcn_mfma_f32_16x16x32_bf16(aq[mf], bk[0], acc2[mf][0], 0, 0, 0);
            acc2[mf][1] = __builtin_amdgcn_mfma_f32_16x16x32_bf16(aq[mf], bk[1], acc2[mf][1], 0, 0, 0);
        }

        if ((fmask8 >> st) & 1) {
            // ---- flush unit u: cols [prev..st]*32, wc quarters prev>>1 .. st>>1 ----
            const int wc0 = prev >> 1, wc1 = st >> 1;
            float rn[2];
#pragma unroll
            for (int nf = 0; nf < 2; ++nf) {
                int key = kq * 32 + nf * 16 + l15;
                float nv = 0.f;
                for (int q2 = wc0; q2 <= wc1; ++q2) nv += normP[q2 * 128 + key];
                rn[nf] = 1.0f / fmaxf(sqrtf(nv), 1e-3f);
            }
#pragma unroll
            for (int mf = 0; mf < 8; ++mf) {
#pragma unroll
                for (int e = 0; e < 4; ++e) {
                    float v0 = acc2[mf][0][e] * rn[0];
                    float v1 = acc2[mf][1][e] * rn[1];
                    float bv; int bi5;
                    if (v1 > v0) { bv = v1; bi5 = 16 + l15; }
                    else         { bv = v0; bi5 = l15; }
                    unsigned int ui = __float_as_uint(bv);
                    unsigned int mp = ui ^ (((int)ui < 0) ? 0xFFFFFFFFu : 0x80000000u);
                    unsigned int enc = (mp & 0xFFFFFFC0u) | (63u - (unsigned int)bi5);
#pragma unroll
                    for (int mask = 1; mask <= 8; mask <<= 1) {
                        unsigned int o = __shfl_xor(enc, mask);
                        enc = (o > enc) ? o : enc;
                    }
                    if (l15 == 0) {
                        unsigned int gl = (unsigned int)(kb + kq * 32 + (63 - (int)(enc & 63u)));
                        unsigned long long e64 =
                            ((unsigned long long)(enc & 0xFFFFFFC0u) << 32) |
                            (unsigned long long)(0xFFFFFFFFu - gl);
                        int qq = qh * 128 + mf * 16 + lg * 4 + e;
                        unsigned long long* addr = best + u * BZn + qq;
                        if (e64 > *addr) atomicMax(addr, e64);
                    }
                    acc2[mf][0][e] = 0.f;
                    acc2[mf][1][e] = 0.f;
                }
            }
            ++u;
            prev = st + 1;
        }
    }
}

// ---------------- finish: exact f32 cosine of the winners ----------------
__global__ void k_final(const float* __restrict__ keys, const float* __restrict__ R,
                        const float* __restrict__ Qrot,
                        const unsigned long long* __restrict__ best, float* __restrict__ out) {
    const int fid = blockIdx.x;
    const int u = fid >> 8, b = fid & 255;
    int off, d;
    if (u < 2)      { off = u * 256;            d = 256; }
    else if (u < 5) { off = 512 + (u - 2) * 128; d = 128; }
    else            { off = 896 + (u - 5) * 64;  d = 64;  }

    unsigned long long ent = best[fid];
    if (ent == 0ull) return;

    __shared__ float krow[Hd];
    __shared__ float red[12];
    const int t = threadIdx.x;
    unsigned int gl = 0xFFFFFFFFu - (unsigned int)(ent & 0xFFFFFFFFull);
    const float* kp = keys + (long long)gl * Hd;
    *(float4*)(&krow[t * 4]) = *(const float4*)(kp + t * 4);
    __syncthreads();

    float pn = 0.f, pq = 0.f, pk = 0.f;
    if (t < d) {
        float kr = 0.f;
        for (int k = 0; k < Hd; ++k) kr += krow[k] * R[(long long)k * Hd + off + t];
        float qv = Qrot[(long long)b * Hd + off + t];
        pn = qv * kr; pq = qv * qv; pk = kr * kr;
    }
    for (int mask = 1; mask <= 32; mask <<= 1) {
        pn += __shfl_xor(pn, mask); pq += __shfl_xor(pq, mask); pk += __shfl_xor(pk, mask);
    }
    if ((t & 63) == 0) { red[t >> 6] = pn; red[4 + (t >> 6)] = pq; red[8 + (t >> 6)] = pk; }
    __syncthreads();
    if (t == 0) {
        float nm = red[0] + red[1] + red[2] + red[3];
        float qq = red[4] + red[5] + red[6] + red[7];
        float kk = red[8] + red[9] + red[10] + red[11];
        float cosv = nm / (fmaxf(sqrtf(qq), 1e-8f) * fmaxf(sqrtf(kk), 1e-8f));
        atomicAdd(out, -cosv * (float)d / (256.0f * 1024.0f));
    }
}

// ---------------- launch ----------------
extern "C" void kernel_launch(void* const* d_in, const int* in_sizes, int n_in,
                              void* d_out, int out_size, void* d_ws, size_t ws_size,
                              hipStream_t stream) {
    (void)in_sizes; (void)n_in; (void)out_size; (void)ws_size;
    const float* query = (const float*)d_in[0];
    const float* keys  = (const float*)d_in[1];
    const float* R     = (const float*)d_in[2];
    float* out = (float*)d_out;
    char* ws = (char*)d_ws;

    unsigned long long* best = (unsigned long long*)ws;           // 16 KiB slot
    float* Qrot   = (float*)(ws + 16384);                         // 1 MiB
    u16*   Rpack  = (u16*)(ws + 16384 + 1048576);                 // 2 MiB
    u16*   Qpack  = (u16*)(ws + 16384 + 1048576 + 2097152);       // 512 KiB

    hipMemsetAsync(best, 0, NU * BZn * sizeof(unsigned long long), stream);
    hipMemsetAsync(out, 0, sizeof(float), stream);

    k_qrot <<<64,  256, 0, stream>>>(query, R, Qrot);
    k_rpack<<<512, 256, 0, stream>>>(R, Rpack);
    k_qpack<<<128, 256, 0, stream>>>(Qrot, Qpack);

    hipFuncSetAttribute((const void*)k_fused,
                        hipFuncAttributeMaxDynamicSharedMemorySize, LDS_TOT);
    k_fused<<<(MTOT / 128) * 4, 512, LDS_TOT, stream>>>(keys, Rpack, Qpack, best);

    k_final<<<NU * BZn, 256, 0, stream>>>(keys, R, Qrot, best, out);
}